// Round 3
// baseline (5533.275 us; speedup 1.0000x reference)
//
#include <hip/hip_runtime.h>
#include <hip/hip_bf16.h>
#include <math.h>

// HAN: word bi-GRU + attention -> sentence bi-GRU + attention -> doc vector.
// Split-bf16 (hi+lo) MFMA for big GEMMs; f32 vector math for gates/attention.
// R3: persistent recurrent kernels (grid barrier), LDS-resident Whh slices,
//     transposed xW layout, parallelized word attention.

typedef __attribute__((ext_vector_type(8))) short short8;
typedef __attribute__((ext_vector_type(4))) float f32x4;

__device__ __forceinline__ unsigned short f2bf(float f) {
    unsigned int u = __float_as_uint(f);
    u += 0x7fff + ((u >> 16) & 1);   // RNE
    return (unsigned short)(u >> 16);
}
__device__ __forceinline__ float bf2f(unsigned short u) {
    return __uint_as_float(((unsigned int)u) << 16);
}
__device__ __forceinline__ float sigmoidf_(float x) { return 1.f / (1.f + expf(-x)); }

__device__ __forceinline__ f32x4 mfma16(short8 a, short8 b, f32x4 c) {
    return __builtin_amdgcn_mfma_f32_16x16x32_bf16(a, b, c, 0, 0, 0);
}

// Sense-free generation grid barrier (agent scope). All threads call it.
__device__ __forceinline__ void grid_barrier(unsigned* cnt, unsigned* gen, unsigned nblk) {
    __syncthreads();
    if (threadIdx.x == 0) {
        unsigned g = __hip_atomic_load(gen, __ATOMIC_RELAXED, __HIP_MEMORY_SCOPE_AGENT);
        unsigned old = __hip_atomic_fetch_add(cnt, 1u, __ATOMIC_ACQ_REL, __HIP_MEMORY_SCOPE_AGENT);
        if (old == nblk - 1u) {
            __hip_atomic_store(cnt, 0u, __ATOMIC_RELAXED, __HIP_MEMORY_SCOPE_AGENT);
            __hip_atomic_store(gen, g + 1u, __ATOMIC_RELEASE, __HIP_MEMORY_SCOPE_AGENT);
        } else {
            unsigned cur;
            do {
                __builtin_amdgcn_s_sleep(2);
                cur = __hip_atomic_load(gen, __ATOMIC_ACQUIRE, __HIP_MEMORY_SCOPE_AGENT);
            } while (cur == g);
        }
    }
    __syncthreads();
}

// ---------------- split f32 -> (hi,lo) bf16 ----------------
__global__ __launch_bounds__(256) void split_f32(const float* __restrict__ src,
                                                 unsigned short* __restrict__ hi,
                                                 unsigned short* __restrict__ lo, int n) {
    int i = blockIdx.x * blockDim.x + threadIdx.x;
    int stride = gridDim.x * blockDim.x;
    for (; i < n; i += stride) {
        float v = src[i];
        unsigned short h = f2bf(v);
        hi[i] = h;
        lo[i] = f2bf(v - bf2f(h));
    }
}

// ---------------- split-bf16 MFMA GEMM (NT): C[m][n] = sum_k A[m][k]*B[n][k] + bias[n]
// tr96: store row m = s*96+pos transposed to pos*96+s (for xWt layout).
__global__ __launch_bounds__(256) void gemm_split(
    const float* __restrict__ A, const int* __restrict__ tokens,
    const unsigned short* __restrict__ Bhi, const unsigned short* __restrict__ Blo,
    const float* __restrict__ bias, float* __restrict__ C,
    int M, int N, int K, int tr96)
{
    __shared__ unsigned short Ah[64][40], Al[64][40];
    __shared__ unsigned short Bh[128][40], Bl[128][40];

    int t = threadIdx.x;
    int m0 = blockIdx.x * 64, n0 = blockIdx.y * 128;
    int wave = t >> 6, lane = t & 63;
    int wm = wave >> 1, wn = wave & 1;
    int kg = lane >> 4, r16 = lane & 15;

    f32x4 acc[2][4];
#pragma unroll
    for (int i = 0; i < 2; i++)
#pragma unroll
        for (int j = 0; j < 4; j++)
#pragma unroll
            for (int q = 0; q < 4; q++) acc[i][j][q] = 0.f;

    int ar = t >> 2, ac8 = (t & 3) * 8;
    long arow = -1;
    if (m0 + ar < M) arow = tokens ? (long)tokens[m0 + ar] : (long)(m0 + ar);

    for (int kt = 0; kt < K; kt += 32) {
        {
            short8 hv, lv;
            if (arow >= 0) {
                const float* ap = A + arow * (long)K + kt + ac8;
                f32x4 u0 = *(const f32x4*)ap;
                f32x4 u1 = *(const f32x4*)(ap + 4);
#pragma unroll
                for (int i = 0; i < 8; i++) {
                    float x = (i < 4) ? u0[i] : u1[i - 4];
                    unsigned short hb = f2bf(x);
                    hv[i] = (short)hb;
                    lv[i] = (short)f2bf(x - bf2f(hb));
                }
            } else {
#pragma unroll
                for (int i = 0; i < 8; i++) { hv[i] = 0; lv[i] = 0; }
            }
            *(short8*)&Ah[ar][ac8] = hv;
            *(short8*)&Al[ar][ac8] = lv;
        }
#pragma unroll
        for (int i = 0; i < 2; i++) {
            int idx = t + i * 256;
            int br = idx >> 2, bc8 = (idx & 3) * 8;
            long go = (long)(n0 + br) * K + kt + bc8;
            *(short8*)&Bh[br][bc8] = *(const short8*)(Bhi + go);
            *(short8*)&Bl[br][bc8] = *(const short8*)(Blo + go);
        }
        __syncthreads();

        short8 afh[2], afl[2], bfh[4], bfl[4];
#pragma unroll
        for (int m16 = 0; m16 < 2; m16++) {
            afh[m16] = *(short8*)&Ah[wm * 32 + m16 * 16 + r16][kg * 8];
            afl[m16] = *(short8*)&Al[wm * 32 + m16 * 16 + r16][kg * 8];
        }
#pragma unroll
        for (int n16 = 0; n16 < 4; n16++) {
            bfh[n16] = *(short8*)&Bh[wn * 64 + n16 * 16 + r16][kg * 8];
            bfl[n16] = *(short8*)&Bl[wn * 64 + n16 * 16 + r16][kg * 8];
        }
#pragma unroll
        for (int m16 = 0; m16 < 2; m16++)
#pragma unroll
            for (int n16 = 0; n16 < 4; n16++) {
                acc[m16][n16] = mfma16(afh[m16], bfh[n16], acc[m16][n16]);
                acc[m16][n16] = mfma16(afh[m16], bfl[n16], acc[m16][n16]);
                acc[m16][n16] = mfma16(afl[m16], bfh[n16], acc[m16][n16]);
            }
        __syncthreads();
    }

#pragma unroll
    for (int m16 = 0; m16 < 2; m16++)
#pragma unroll
        for (int n16 = 0; n16 < 4; n16++)
#pragma unroll
            for (int q = 0; q < 4; q++) {
                int row = m0 + wm * 32 + m16 * 16 + kg * 4 + q;
                int col = n0 + wn * 64 + n16 * 16 + r16;
                if (row < M) {
                    long crow = tr96 ? (long)((row % 96) * 96 + row / 96) : (long)row;
                    C[crow * N + col] = acc[m16][n16][q] + bias[col];
                }
            }
}

// ---------------- persistent word bi-GRU ----------------
// 256 blocks x 192 thr. block = (msplit = blk&1, j-tile = blk>>1, 8 j each).
// Whh hi+lo slice (24 rows x 1024) LDS-resident, granule-major layout.
// Per step: A (h) direct global->reg from L2; 1 grid barrier; h double-buffered.
__global__ __launch_bounds__(192) void word_rnn(
    const unsigned short* __restrict__ Whi, const unsigned short* __restrict__ Wlo,
    unsigned short* __restrict__ hhiA, unsigned short* __restrict__ hloA,
    unsigned short* __restrict__ hhiB, unsigned short* __restrict__ hloB,
    const float* __restrict__ xWt,   // [96 pos][96 s][3072]
    const float* __restrict__ bhh, float* __restrict__ bi,
    unsigned* bar_cnt, unsigned* bar_gen)
{
    __shared__ unsigned short Bh[128 * 24 * 8];   // 48KB, [kg][row][8]
    __shared__ unsigned short Bl[128 * 24 * 8];   // 48KB

    int t = threadIdx.x;
    int blk = blockIdx.x;
    int msplit = blk & 1;
    int j0 = (blk >> 1) * 8;
    int w = t >> 6, lane = t & 63, kg4 = lane >> 4, r16 = lane & 15;

    // one-time Whh slice fill (rows: g*8+jl)
    for (int i = t; i < 3072; i += 192) {
        int kgg = i & 127, row = i >> 7;
        long src = (long)((row >> 3) * 1024 + j0 + (row & 7)) * 1024 + kgg * 8;
        *(short8*)&Bh[(kgg * 24 + row) * 8] = *(const short8*)(Whi + src);
        *(short8*)&Bl[(kgg * 24 + row) * 8] = *(const short8*)(Wlo + src);
    }
    __syncthreads();

    const unsigned short* rhi = hhiB;
    const unsigned short* rlo = hloB;
    unsigned short* whi = hhiA;
    unsigned short* wlo = hloA;

    int jl = r16 & 7;
    int brow1 = 16 + jl;
    long a0base = (long)(msplit * 96 + (w * 2 + 0) * 16 + r16) * 1024 + kg4 * 8;
    long a1base = a0base + 16 * 1024;

    for (int tau = 0; tau < 96; tau++) {
        int pos = msplit ? (95 - tau) : tau;
        // prefetch xW values (epilogue operands) into registers
        float xwv[2][4][3];
#pragma unroll
        for (int mi = 0; mi < 2; mi++)
#pragma unroll
            for (int q = 0; q < 4; q++) {
                int s = (w * 2 + mi) * 16 + kg4 * 4 + q;
                const float* xp = xWt + ((long)pos * 96 + s) * 3072 + j0 + jl;
                xwv[mi][q][0] = xp[0];
                xwv[mi][q][1] = xp[1024];
                xwv[mi][q][2] = xp[2048];
            }

        f32x4 acc[2][2];
#pragma unroll
        for (int i = 0; i < 2; i++)
#pragma unroll
            for (int j = 0; j < 2; j++)
#pragma unroll
                for (int q = 0; q < 4; q++) acc[i][j][q] = 0.f;

        if (tau > 0) {
#pragma unroll 4
            for (int ki = 0; ki < 32; ki++) {
                short8 ah0 = *(const short8*)(rhi + a0base + ki * 32);
                short8 al0 = *(const short8*)(rlo + a0base + ki * 32);
                short8 ah1 = *(const short8*)(rhi + a1base + ki * 32);
                short8 al1 = *(const short8*)(rlo + a1base + ki * 32);
                int kgg = ki * 4 + kg4;
                short8 b0h = *(short8*)&Bh[(kgg * 24 + r16) * 8];
                short8 b0l = *(short8*)&Bl[(kgg * 24 + r16) * 8];
                short8 b1h = *(short8*)&Bh[(kgg * 24 + brow1) * 8];
                short8 b1l = *(short8*)&Bl[(kgg * 24 + brow1) * 8];
                acc[0][0] = mfma16(ah0, b0h, acc[0][0]);
                acc[0][0] = mfma16(ah0, b0l, acc[0][0]);
                acc[0][0] = mfma16(al0, b0h, acc[0][0]);
                acc[0][1] = mfma16(ah0, b1h, acc[0][1]);
                acc[0][1] = mfma16(ah0, b1l, acc[0][1]);
                acc[0][1] = mfma16(al0, b1h, acc[0][1]);
                acc[1][0] = mfma16(ah1, b0h, acc[1][0]);
                acc[1][0] = mfma16(ah1, b0l, acc[1][0]);
                acc[1][0] = mfma16(al1, b0h, acc[1][0]);
                acc[1][1] = mfma16(ah1, b1h, acc[1][1]);
                acc[1][1] = mfma16(ah1, b1l, acc[1][1]);
                acc[1][1] = mfma16(al1, b1h, acc[1][1]);
            }
        }

        // epilogue: lane r16<8 holds gate0 (acc[mi][0]) and gate2 (acc[mi][1]);
        // gate1 lives in lane r16+8's acc[mi][0].
        int j = j0 + jl;
        float b_r = bhh[j], b_z = bhh[1024 + j], b_n = bhh[2048 + j];
#pragma unroll
        for (int mi = 0; mi < 2; mi++) {
#pragma unroll
            for (int q = 0; q < 4; q++) {
                float g0 = acc[mi][0][q];
                float g1 = __shfl_xor(g0, 8);
                float g2 = acc[mi][1][q];
                if (r16 < 8) {
                    int s = (w * 2 + mi) * 16 + kg4 * 4 + q;
                    int b = msplit * 96 + s;
                    float rr = sigmoidf_(xwv[mi][q][0] + g0 + b_r);
                    float zz = sigmoidf_(xwv[mi][q][1] + g1 + b_z);
                    float nn = tanhf(xwv[mi][q][2] + rr * (g2 + b_n));
                    long o = (long)b * 1024 + j;
                    float hprev = 0.f;
                    if (tau > 0) hprev = bf2f(rhi[o]) + bf2f(rlo[o]);
                    float hnew = (1.f - zz) * nn + zz * hprev;
                    unsigned short hh = f2bf(hnew);
                    whi[o] = hh;
                    wlo[o] = f2bf(hnew - bf2f(hh));
                    bi[((long)s * 96 + pos) * 2048 + msplit * 1024 + j] = hnew;
                }
            }
        }

        if (tau != 95) grid_barrier(bar_cnt, bar_gen, 256);
        // swap buffers
        const unsigned short* th = whi; const unsigned short* tl = wlo;
        whi = (unsigned short*)rhi; wlo = (unsigned short*)rlo;
        rhi = th; rlo = tl;
    }
}

// ---------------- word attention, two parallel kernels ----------------
__global__ __launch_bounds__(256) void wscore(
    const float* __restrict__ bi, const float* __restrict__ wctx,
    const float* __restrict__ wctx_b, float* __restrict__ wsc)
{
    int tok = blockIdx.x * 4 + (threadIdx.x >> 6);
    int lane = threadIdx.x & 63;
    const float* row = bi + (long)tok * 2048 + lane * 32;
    const float* cp = wctx + lane * 32;
    float p = 0.f;
#pragma unroll
    for (int i = 0; i < 32; i += 4) {
        f32x4 v = *(const f32x4*)(row + i);
        f32x4 c = *(const f32x4*)(cp + i);
        p += v[0] * c[0] + v[1] * c[1] + v[2] * c[2] + v[3] * c[3];
    }
    p += __shfl_xor(p, 32); p += __shfl_xor(p, 16); p += __shfl_xor(p, 8);
    p += __shfl_xor(p, 4);  p += __shfl_xor(p, 2);  p += __shfl_xor(p, 1);
    if (lane == 0) wsc[tok] = expf(p + wctx_b[0]);
}

__global__ __launch_bounds__(256) void wsum(
    const float* __restrict__ bi, const float* __restrict__ wsc,
    float* __restrict__ sent_vecs)
{
    int s = blockIdx.x;
    int c = blockIdx.y * 256 + threadIdx.x;
    float acc = 0.f;
    for (int tk = 0; tk < 96; tk++)
        acc += wsc[s * 96 + tk] * bi[((long)s * 96 + tk) * 2048 + c];
    sent_vecs[(long)s * 2048 + c] = acc;
}

// ---------------- persistent sentence bi-GRU ----------------
// 128 blocks x 256 thr; sWhh f32 slice (24 rows x 1024) LDS-resident.
__global__ __launch_bounds__(256) void sent_rnn(
    const float* __restrict__ sWhh, const float* __restrict__ xWs,
    const float* __restrict__ sbhh, float* __restrict__ hA, float* __restrict__ hB,
    float* __restrict__ sbi, unsigned* bar_cnt, unsigned* bar_gen)
{
    __shared__ float Wl[24 * 1028];     // padded rows
    __shared__ float hsh[2048];
    __shared__ float part[4][48];

    int t = threadIdx.x;
    int j0 = blockIdx.x * 8;
    int w = t >> 6, lane = t & 63;

    for (int i = t; i < 24 * 1024; i += 256) {
        int row = i >> 10, k = i & 1023;
        Wl[row * 1028 + k] = sWhh[(long)((row >> 3) * 1024 + j0 + (row & 7)) * 1024 + k];
    }

    float* rbuf = hB;
    float* wbuf = hA;

    for (int tau = 0; tau < 96; tau++) {
        __syncthreads();
        for (int i = t; i < 2048; i += 256) hsh[i] = (tau > 0) ? rbuf[i] : 0.f;
        __syncthreads();

        if (lane < 48) {
            int row = lane >> 1, bq = lane & 1;
            const float* wp = &Wl[row * 1028 + w * 256];
            const float* hp = &hsh[bq * 1024 + w * 256];
            float accd = 0.f;
            for (int k = 0; k < 256; k += 4) {
                f32x4 wv = *(const f32x4*)(wp + k);
                f32x4 hv = *(const f32x4*)(hp + k);
                accd += wv[0] * hv[0] + wv[1] * hv[1] + wv[2] * hv[2] + wv[3] * hv[3];
            }
            part[w][lane] = accd;
        }
        __syncthreads();

        if (t < 16) {
            int jl2 = t >> 1, bq = t & 1;
            int j = j0 + jl2;
            int pos = bq ? (95 - tau) : tau;
            const float* xp = xWs + (long)pos * 3072;
            int d0 = (0 * 8 + jl2) * 2 + bq;
            int d1 = (1 * 8 + jl2) * 2 + bq;
            int d2 = (2 * 8 + jl2) * 2 + bq;
            float D0 = part[0][d0] + part[1][d0] + part[2][d0] + part[3][d0];
            float D1 = part[0][d1] + part[1][d1] + part[2][d1] + part[3][d1];
            float D2 = part[0][d2] + part[1][d2] + part[2][d2] + part[3][d2];
            float rr = sigmoidf_(xp[j] + D0 + sbhh[j]);
            float zz = sigmoidf_(xp[1024 + j] + D1 + sbhh[1024 + j]);
            float nn = tanhf(xp[2048 + j] + rr * (D2 + sbhh[2048 + j]));
            float hprev = (tau > 0) ? rbuf[bq * 1024 + j] : 0.f;
            float hnew = (1.f - zz) * nn + zz * hprev;
            wbuf[bq * 1024 + j] = hnew;
            sbi[(long)pos * 2048 + bq * 1024 + j] = hnew;
        }

        if (tau != 95) grid_barrier(bar_cnt, bar_gen, 128);
        float* tmp = wbuf; wbuf = rbuf; rbuf = tmp;
    }
}

// ---------------- sentence attention ----------------
__global__ __launch_bounds__(256) void sent_scores(
    const float* __restrict__ sbi, const float* __restrict__ sctx,
    const float* __restrict__ sctx_b, float* __restrict__ scores)
{
    __shared__ float red[4];
    int s = blockIdx.x, t = threadIdx.x, c = t * 8;
    const float* row = sbi + (long)s * 2048 + c;
    float p = 0.f;
#pragma unroll
    for (int i = 0; i < 8; i++) p += row[i] * sctx[c + i];
    p += __shfl_xor(p, 32); p += __shfl_xor(p, 16); p += __shfl_xor(p, 8);
    p += __shfl_xor(p, 4);  p += __shfl_xor(p, 2);  p += __shfl_xor(p, 1);
    int lane = t & 63, w = t >> 6;
    if (lane == 0) red[w] = p;
    __syncthreads();
    if (t == 0) scores[s] = expf(red[0] + red[1] + red[2] + red[3] + sctx_b[0]);
}

__global__ __launch_bounds__(256) void doc_out(
    const float* __restrict__ sbi, const float* __restrict__ scores,
    float* __restrict__ out)
{
    int t = threadIdx.x, c = t * 8;
    float acc[8];
#pragma unroll
    for (int i = 0; i < 8; i++) acc[i] = 0.f;
    for (int s = 0; s < 96; s++) {
        float sc = scores[s];
        const float* row = sbi + (long)s * 2048 + c;
#pragma unroll
        for (int i = 0; i < 8; i++) acc[i] += sc * row[i];
    }
#pragma unroll
    for (int i = 0; i < 8; i++) out[c + i] = acc[i];
}

// ---------------- host ----------------
extern "C" void kernel_launch(void* const* d_in, const int* in_sizes, int n_in,
                              void* d_out, int out_size, void* d_ws, size_t ws_size,
                              hipStream_t stream)
{
    const int*   tokens    = (const int*)  d_in[0];
    const float* embedding = (const float*)d_in[1];
    const float* wWih = (const float*)d_in[2];
    const float* wWhh = (const float*)d_in[3];
    const float* wbih = (const float*)d_in[4];
    const float* wbhh = (const float*)d_in[5];
    const float* sWih = (const float*)d_in[6];
    const float* sWhh = (const float*)d_in[7];
    const float* sbih = (const float*)d_in[8];
    const float* sbhh = (const float*)d_in[9];
    const float* wctxw = (const float*)d_in[10];
    const float* wctxb = (const float*)d_in[11];
    const float* sctxw = (const float*)d_in[12];
    const float* sctxb = (const float*)d_in[13];
    float* out = (float*)d_out;

    char* p = (char*)d_ws;
    auto alloc = [&](size_t bytes) -> char* {
        char* r = p;
        p += (bytes + 255) & ~(size_t)255;
        return r;
    };
    unsigned short* WihHi  = (unsigned short*)alloc(3072l * 1024 * 2);
    unsigned short* WihLo  = (unsigned short*)alloc(3072l * 1024 * 2);
    unsigned short* WhhHi  = (unsigned short*)alloc(3072l * 1024 * 2);
    unsigned short* WhhLo  = (unsigned short*)alloc(3072l * 1024 * 2);
    unsigned short* sWihHi = (unsigned short*)alloc(3072l * 2048 * 2);
    unsigned short* sWihLo = (unsigned short*)alloc(3072l * 2048 * 2);
    float* xWt       = (float*)alloc(9216l * 3072 * 4);   // [pos][s][3072]
    float* bi        = (float*)alloc(9216l * 2048 * 4);
    unsigned short* hAhi = (unsigned short*)alloc(192l * 1024 * 2);
    unsigned short* hAlo = (unsigned short*)alloc(192l * 1024 * 2);
    unsigned short* hBhi = (unsigned short*)alloc(192l * 1024 * 2);
    unsigned short* hBlo = (unsigned short*)alloc(192l * 1024 * 2);
    float* sent_vecs = (float*)alloc(96l * 2048 * 4);
    float* xWs       = (float*)alloc(96l * 3072 * 4);
    float* hsA       = (float*)alloc(2l * 1024 * 4);
    float* hsB       = (float*)alloc(2l * 1024 * 4);
    float* sbi       = (float*)alloc(96l * 2048 * 4);
    float* scores    = (float*)alloc(512);
    float* wsc       = (float*)alloc(9216l * 4);
    unsigned* barbuf = (unsigned*)alloc(256);
    (void)ws_size; (void)in_sizes; (void)n_in; (void)out_size;

    hipMemsetAsync(barbuf, 0, 256, stream);

    split_f32<<<1024, 256, 0, stream>>>(wWih, WihHi, WihLo, 3072 * 1024);
    split_f32<<<1024, 256, 0, stream>>>(wWhh, WhhHi, WhhLo, 3072 * 1024);
    split_f32<<<1024, 256, 0, stream>>>(sWih, sWihHi, sWihLo, 3072 * 2048);

    // word input projection, stored transposed: xWt[pos][s][3072]
    gemm_split<<<dim3(144, 24), 256, 0, stream>>>(
        embedding, tokens, WihHi, WihLo, wbih, xWt, 9216, 3072, 1024, 1);

    // persistent word bi-GRU (96 steps internally)
    word_rnn<<<256, 192, 0, stream>>>(
        WhhHi, WhhLo, hAhi, hAlo, hBhi, hBlo, xWt, wbhh, bi,
        barbuf + 0, barbuf + 16);

    // word attention
    wscore<<<2304, 256, 0, stream>>>(bi, wctxw, wctxb, wsc);
    wsum<<<dim3(96, 8), 256, 0, stream>>>(bi, wsc, sent_vecs);

    // sentence input projection: xWs[pos][3072]
    gemm_split<<<dim3(2, 24), 256, 0, stream>>>(
        sent_vecs, nullptr, sWihHi, sWihLo, sbih, xWs, 96, 3072, 2048, 0);

    // persistent sentence bi-GRU
    sent_rnn<<<128, 256, 0, stream>>>(
        sWhh, xWs, sbhh, hsA, hsB, sbi, barbuf + 32, barbuf + 48);

    sent_scores<<<96, 256, 0, stream>>>(sbi, sctxw, sctxb, scores);
    doc_out<<<1, 256, 0, stream>>>(sbi, scores, out);
}

// Round 4
// 5310.386 us; speedup vs baseline: 1.0420x; 1.0420x over previous
//
#include <hip/hip_runtime.h>
#include <hip/hip_bf16.h>
#include <math.h>

// HAN: word bi-GRU + attention -> sentence bi-GRU + attention -> doc vector.
// Split-bf16 (hi+lo) MFMA for big GEMMs; f32 vector math for gates/attention.
// R4: word_rnn rebuilt -- cooperative double-buffered LDS staging of h with a
// 2-chunk-deep register pipeline (bulk coalesced loads -> latency amortized),
// Whh slice LDS-resident, 6 waves/block, in-register gate fusion.

typedef __attribute__((ext_vector_type(8))) short short8;
typedef __attribute__((ext_vector_type(4))) float f32x4;

__device__ __forceinline__ unsigned short f2bf(float f) {
    unsigned int u = __float_as_uint(f);
    u += 0x7fff + ((u >> 16) & 1);   // RNE
    return (unsigned short)(u >> 16);
}
__device__ __forceinline__ float bf2f(unsigned short u) {
    return __uint_as_float(((unsigned int)u) << 16);
}
__device__ __forceinline__ float sigmoidf_(float x) { return 1.f / (1.f + expf(-x)); }

__device__ __forceinline__ f32x4 mfma16(short8 a, short8 b, f32x4 c) {
    return __builtin_amdgcn_mfma_f32_16x16x32_bf16(a, b, c, 0, 0, 0);
}

// Generation grid barrier (agent scope). All threads call it.
__device__ __forceinline__ void grid_barrier(unsigned* cnt, unsigned* gen, unsigned nblk) {
    __syncthreads();
    if (threadIdx.x == 0) {
        unsigned g = __hip_atomic_load(gen, __ATOMIC_RELAXED, __HIP_MEMORY_SCOPE_AGENT);
        unsigned old = __hip_atomic_fetch_add(cnt, 1u, __ATOMIC_ACQ_REL, __HIP_MEMORY_SCOPE_AGENT);
        if (old == nblk - 1u) {
            __hip_atomic_store(cnt, 0u, __ATOMIC_RELAXED, __HIP_MEMORY_SCOPE_AGENT);
            __hip_atomic_store(gen, g + 1u, __ATOMIC_RELEASE, __HIP_MEMORY_SCOPE_AGENT);
        } else {
            unsigned cur;
            do {
                __builtin_amdgcn_s_sleep(2);
                cur = __hip_atomic_load(gen, __ATOMIC_ACQUIRE, __HIP_MEMORY_SCOPE_AGENT);
            } while (cur == g);
        }
    }
    __syncthreads();
}

// ---------------- split f32 -> (hi,lo) bf16 ----------------
__global__ __launch_bounds__(256) void split_f32(const float* __restrict__ src,
                                                 unsigned short* __restrict__ hi,
                                                 unsigned short* __restrict__ lo, int n) {
    int i = blockIdx.x * blockDim.x + threadIdx.x;
    int stride = gridDim.x * blockDim.x;
    for (; i < n; i += stride) {
        float v = src[i];
        unsigned short h = f2bf(v);
        hi[i] = h;
        lo[i] = f2bf(v - bf2f(h));
    }
}

// ---------------- split-bf16 MFMA GEMM (NT): C[m][n] = sum_k A[m][k]*B[n][k] + bias[n]
__global__ __launch_bounds__(256) void gemm_split(
    const float* __restrict__ A, const int* __restrict__ tokens,
    const unsigned short* __restrict__ Bhi, const unsigned short* __restrict__ Blo,
    const float* __restrict__ bias, float* __restrict__ C,
    int M, int N, int K, int tr96)
{
    __shared__ unsigned short Ah[64][40], Al[64][40];
    __shared__ unsigned short Bh[128][40], Bl[128][40];

    int t = threadIdx.x;
    int m0 = blockIdx.x * 64, n0 = blockIdx.y * 128;
    int wave = t >> 6, lane = t & 63;
    int wm = wave >> 1, wn = wave & 1;
    int kg = lane >> 4, r16 = lane & 15;

    f32x4 acc[2][4];
#pragma unroll
    for (int i = 0; i < 2; i++)
#pragma unroll
        for (int j = 0; j < 4; j++)
#pragma unroll
            for (int q = 0; q < 4; q++) acc[i][j][q] = 0.f;

    int ar = t >> 2, ac8 = (t & 3) * 8;
    long arow = -1;
    if (m0 + ar < M) arow = tokens ? (long)tokens[m0 + ar] : (long)(m0 + ar);

    for (int kt = 0; kt < K; kt += 32) {
        {
            short8 hv, lv;
            if (arow >= 0) {
                const float* ap = A + arow * (long)K + kt + ac8;
                f32x4 u0 = *(const f32x4*)ap;
                f32x4 u1 = *(const f32x4*)(ap + 4);
#pragma unroll
                for (int i = 0; i < 8; i++) {
                    float x = (i < 4) ? u0[i] : u1[i - 4];
                    unsigned short hb = f2bf(x);
                    hv[i] = (short)hb;
                    lv[i] = (short)f2bf(x - bf2f(hb));
                }
            } else {
#pragma unroll
                for (int i = 0; i < 8; i++) { hv[i] = 0; lv[i] = 0; }
            }
            *(short8*)&Ah[ar][ac8] = hv;
            *(short8*)&Al[ar][ac8] = lv;
        }
#pragma unroll
        for (int i = 0; i < 2; i++) {
            int idx = t + i * 256;
            int br = idx >> 2, bc8 = (idx & 3) * 8;
            long go = (long)(n0 + br) * K + kt + bc8;
            *(short8*)&Bh[br][bc8] = *(const short8*)(Bhi + go);
            *(short8*)&Bl[br][bc8] = *(const short8*)(Blo + go);
        }
        __syncthreads();

        short8 afh[2], afl[2], bfh[4], bfl[4];
#pragma unroll
        for (int m16 = 0; m16 < 2; m16++) {
            afh[m16] = *(short8*)&Ah[wm * 32 + m16 * 16 + r16][kg * 8];
            afl[m16] = *(short8*)&Al[wm * 32 + m16 * 16 + r16][kg * 8];
        }
#pragma unroll
        for (int n16 = 0; n16 < 4; n16++) {
            bfh[n16] = *(short8*)&Bh[wn * 64 + n16 * 16 + r16][kg * 8];
            bfl[n16] = *(short8*)&Bl[wn * 64 + n16 * 16 + r16][kg * 8];
        }
#pragma unroll
        for (int m16 = 0; m16 < 2; m16++)
#pragma unroll
            for (int n16 = 0; n16 < 4; n16++) {
                acc[m16][n16] = mfma16(afh[m16], bfh[n16], acc[m16][n16]);
                acc[m16][n16] = mfma16(afh[m16], bfl[n16], acc[m16][n16]);
                acc[m16][n16] = mfma16(afl[m16], bfh[n16], acc[m16][n16]);
            }
        __syncthreads();
    }

#pragma unroll
    for (int m16 = 0; m16 < 2; m16++)
#pragma unroll
        for (int n16 = 0; n16 < 4; n16++)
#pragma unroll
            for (int q = 0; q < 4; q++) {
                int row = m0 + wm * 32 + m16 * 16 + kg * 4 + q;
                int col = n0 + wn * 64 + n16 * 16 + r16;
                if (row < M) {
                    long crow = tr96 ? (long)((row % 96) * 96 + row / 96) : (long)row;
                    C[crow * N + col] = acc[m16][n16][q] + bias[col];
                }
            }
}

// ---------------- persistent word bi-GRU v3 ----------------
// 256 blocks x 384 thr (6 waves). block: msplit = blk>>7 (96 rows), j-slice 8.
// Whh hi+lo slice LDS-resident [arr][kg 0-127][brow 0-23][8]  (96KB).
// h staged via LDS chunks [buf][arr][row 0-95][kgpad 9][8] (55KB), 2-deep pipe.
// Wave w = m16 tile w (rows w*16..+15); 2 n16 tiles: t0 = {g0 j0-7, g1 j0-7},
// t1 = {g2 j0-7, dup}. Gate fusion: one shfl_xor(8).
__global__ __launch_bounds__(384) void word_rnn(
    const unsigned short* __restrict__ Whi, const unsigned short* __restrict__ Wlo,
    unsigned short* __restrict__ hAhi, unsigned short* __restrict__ hAlo,
    unsigned short* __restrict__ hBhi, unsigned short* __restrict__ hBlo,
    const float* __restrict__ xWt,   // [96 pos][96 s][3072]
    const float* __restrict__ bhh, float* __restrict__ bi,
    unsigned* bar_cnt, unsigned* bar_gen)
{
    __shared__ unsigned short Wh[2][128][24][8];    // 96KB
    __shared__ unsigned short As[2][2][96][9][8];   // 55KB (pad 8->9 granules)

    int t = threadIdx.x;
    int blk = blockIdx.x;
    int msplit = blk >> 7;
    int j0 = (blk & 127) * 8;
    int w = t >> 6, lane = t & 63, kg4 = lane >> 4, r16 = lane & 15;

    // one-time Whh slice fill: brow = g*8+jj -> Whh row g*1024 + j0 + jj
    for (int i = t; i < 4096; i += 384) {
        int kg = i >> 5, br = i & 31;
        if (br < 24) {
            long src = (long)((br >> 3) * 1024 + j0 + (br & 7)) * 1024 + kg * 8;
            *(short8*)&Wh[0][kg][br][0] = *(const short8*)(Whi + src);
            *(short8*)&Wh[1][kg][br][0] = *(const short8*)(Wlo + src);
        }
    }

    const unsigned short* rhi = hBhi; const unsigned short* rlo = hBlo;
    unsigned short* whi = hAhi; unsigned short* wlo = hAlo;

    // staging role: thread -> rows (t>>3, t>>3+48), k-granule t&7
    int srow = t >> 3, skg = t & 7;
    int jj = r16 & 7;
    int j = j0 + jj;
    float b_r = bhh[j], b_z = bhh[1024 + j], b_n = bhh[2048 + j];

    short8 vb0[4], vb1[4];

#define LOADC(bank, kc)                                                              \
    do {                                                                             \
        long o0 = (long)(msplit * 96 + srow) * 1024 + (kc) + skg * 8;                \
        long o1 = (long)(msplit * 96 + srow + 48) * 1024 + (kc) + skg * 8;           \
        bank[0] = *(const short8*)(rhi + o0);                                        \
        bank[1] = *(const short8*)(rlo + o0);                                        \
        bank[2] = *(const short8*)(rhi + o1);                                        \
        bank[3] = *(const short8*)(rlo + o1);                                        \
    } while (0)

#define WRITEC(bank, buf)                                                            \
    do {                                                                             \
        *(short8*)&As[buf][0][srow][skg][0] = bank[0];                               \
        *(short8*)&As[buf][1][srow][skg][0] = bank[1];                               \
        *(short8*)&As[buf][0][srow + 48][skg][0] = bank[2];                          \
        *(short8*)&As[buf][1][srow + 48][skg][0] = bank[3];                          \
    } while (0)

#define COMPUTE(buf, kgbase)                                                         \
    do {                                                                             \
        _Pragma("unroll")                                                            \
        for (int ktl = 0; ktl < 2; ktl++) {                                          \
            int kgc = ktl * 4 + kg4;                                                 \
            short8 ah = *(short8*)&As[buf][0][w * 16 + r16][kgc][0];                 \
            short8 al = *(short8*)&As[buf][1][w * 16 + r16][kgc][0];                 \
            int kgB = (kgbase) + kgc;                                                \
            short8 b0h = *(short8*)&Wh[0][kgB][r16][0];                              \
            short8 b0l = *(short8*)&Wh[1][kgB][r16][0];                              \
            short8 b1h = *(short8*)&Wh[0][kgB][16 + jj][0];                          \
            short8 b1l = *(short8*)&Wh[1][kgB][16 + jj][0];                          \
            acc0 = mfma16(ah, b0h, acc0);                                            \
            acc0 = mfma16(ah, b0l, acc0);                                            \
            acc0 = mfma16(al, b0h, acc0);                                            \
            acc1 = mfma16(ah, b1h, acc1);                                            \
            acc1 = mfma16(ah, b1l, acc1);                                            \
            acc1 = mfma16(al, b1h, acc1);                                            \
        }                                                                            \
    } while (0)

    for (int tau = 0; tau < 96; tau++) {
        int pos = msplit ? (95 - tau) : tau;

        // epilogue operand prefetch (producing lanes only)
        float xwv[4][3];
        float hpv[4];
#pragma unroll
        for (int q = 0; q < 4; q++) {
            if (r16 < 8) {
                int hloc = w * 16 + kg4 * 4 + q;
                const float* xp = xWt + ((long)pos * 96 + hloc) * 3072 + j;
                xwv[q][0] = xp[0];
                xwv[q][1] = xp[1024];
                xwv[q][2] = xp[2048];
                long o = (long)(msplit * 96 + hloc) * 1024 + j;
                hpv[q] = bf2f(rhi[o]) + bf2f(rlo[o]);
            } else {
                xwv[q][0] = xwv[q][1] = xwv[q][2] = 0.f;
                hpv[q] = 0.f;
            }
        }

        f32x4 acc0, acc1;
#pragma unroll
        for (int q = 0; q < 4; q++) { acc0[q] = 0.f; acc1[q] = 0.f; }

        // pipeline prologue
        LOADC(vb0, 0);
        LOADC(vb1, 64);
        WRITEC(vb0, 0);
        __syncthreads();

        for (int cp = 0; cp < 8; cp++) {
            int c0 = cp * 2;
            // even chunk
            if (cp < 7) LOADC(vb0, (c0 + 2) * 64);
            COMPUTE(0, c0 * 8);
            WRITEC(vb1, 1);
            __syncthreads();
            // odd chunk
            if (cp < 7) LOADC(vb1, (c0 + 3) * 64);
            COMPUTE(1, c0 * 8 + 8);
            if (cp < 7) {
                WRITEC(vb0, 0);
            }
            __syncthreads();
        }

        // epilogue: acc0 = {g0 (r16<8), g1 (r16>=8)}, acc1 = g2.
#pragma unroll
        for (int q = 0; q < 4; q++) {
            float g0 = acc0[q];
            float g1 = __shfl_xor(g0, 8);
            float g2 = acc1[q];
            if (r16 < 8) {
                int hloc = w * 16 + kg4 * 4 + q;
                float rr = sigmoidf_(xwv[q][0] + g0 + b_r);
                float zz = sigmoidf_(xwv[q][1] + g1 + b_z);
                float nn = tanhf(xwv[q][2] + rr * (g2 + b_n));
                float hnew = (1.f - zz) * nn + zz * hpv[q];
                long o = (long)(msplit * 96 + hloc) * 1024 + j;
                unsigned short hh = f2bf(hnew);
                whi[o] = hh;
                wlo[o] = f2bf(hnew - bf2f(hh));
                bi[((long)hloc * 96 + pos) * 2048 + msplit * 1024 + j] = hnew;
            }
        }

        if (tau != 95) grid_barrier(bar_cnt, bar_gen, 256);
        const unsigned short* th = whi; const unsigned short* tl = wlo;
        whi = (unsigned short*)rhi; wlo = (unsigned short*)rlo;
        rhi = th; rlo = tl;
    }
#undef LOADC
#undef WRITEC
#undef COMPUTE
}

// ---------------- word attention, two parallel kernels ----------------
__global__ __launch_bounds__(256) void wscore(
    const float* __restrict__ bi, const float* __restrict__ wctx,
    const float* __restrict__ wctx_b, float* __restrict__ wsc)
{
    int tok = blockIdx.x * 4 + (threadIdx.x >> 6);
    int lane = threadIdx.x & 63;
    const float* row = bi + (long)tok * 2048 + lane * 32;
    const float* cp = wctx + lane * 32;
    float p = 0.f;
#pragma unroll
    for (int i = 0; i < 32; i += 4) {
        f32x4 v = *(const f32x4*)(row + i);
        f32x4 c = *(const f32x4*)(cp + i);
        p += v[0] * c[0] + v[1] * c[1] + v[2] * c[2] + v[3] * c[3];
    }
    p += __shfl_xor(p, 32); p += __shfl_xor(p, 16); p += __shfl_xor(p, 8);
    p += __shfl_xor(p, 4);  p += __shfl_xor(p, 2);  p += __shfl_xor(p, 1);
    if (lane == 0) wsc[tok] = expf(p + wctx_b[0]);
}

__global__ __launch_bounds__(256) void wsum(
    const float* __restrict__ bi, const float* __restrict__ wsc,
    float* __restrict__ sent_vecs)
{
    int s = blockIdx.x;
    int c = blockIdx.y * 256 + threadIdx.x;
    float acc = 0.f;
    for (int tk = 0; tk < 96; tk++)
        acc += wsc[s * 96 + tk] * bi[((long)s * 96 + tk) * 2048 + c];
    sent_vecs[(long)s * 2048 + c] = acc;
}

// ---------------- persistent sentence bi-GRU ----------------
__global__ __launch_bounds__(256) void sent_rnn(
    const float* __restrict__ sWhh, const float* __restrict__ xWs,
    const float* __restrict__ sbhh, float* __restrict__ hA, float* __restrict__ hB,
    float* __restrict__ sbi, unsigned* bar_cnt, unsigned* bar_gen)
{
    __shared__ float Wl[24 * 1028];
    __shared__ float hsh[2048];
    __shared__ float part[4][48];

    int t = threadIdx.x;
    int j0 = blockIdx.x * 8;
    int w = t >> 6, lane = t & 63;

    for (int i = t; i < 24 * 1024; i += 256) {
        int row = i >> 10, k = i & 1023;
        Wl[row * 1028 + k] = sWhh[(long)((row >> 3) * 1024 + j0 + (row & 7)) * 1024 + k];
    }

    float* rbuf = hB;
    float* wbuf = hA;

    for (int tau = 0; tau < 96; tau++) {
        __syncthreads();
        for (int i = t; i < 2048; i += 256) hsh[i] = (tau > 0) ? rbuf[i] : 0.f;
        __syncthreads();

        if (lane < 48) {
            int row = lane >> 1, bq = lane & 1;
            const float* wp = &Wl[row * 1028 + w * 256];
            const float* hp = &hsh[bq * 1024 + w * 256];
            float accd = 0.f;
            for (int k = 0; k < 256; k += 4) {
                f32x4 wv = *(const f32x4*)(wp + k);
                f32x4 hv = *(const f32x4*)(hp + k);
                accd += wv[0] * hv[0] + wv[1] * hv[1] + wv[2] * hv[2] + wv[3] * hv[3];
            }
            part[w][lane] = accd;
        }
        __syncthreads();

        if (t < 16) {
            int jl2 = t >> 1, bq = t & 1;
            int j = j0 + jl2;
            int pos = bq ? (95 - tau) : tau;
            const float* xp = xWs + (long)pos * 3072;
            int d0 = (0 * 8 + jl2) * 2 + bq;
            int d1 = (1 * 8 + jl2) * 2 + bq;
            int d2 = (2 * 8 + jl2) * 2 + bq;
            float D0 = part[0][d0] + part[1][d0] + part[2][d0] + part[3][d0];
            float D1 = part[0][d1] + part[1][d1] + part[2][d1] + part[3][d1];
            float D2 = part[0][d2] + part[1][d2] + part[2][d2] + part[3][d2];
            float rr = sigmoidf_(xp[j] + D0 + sbhh[j]);
            float zz = sigmoidf_(xp[1024 + j] + D1 + sbhh[1024 + j]);
            float nn = tanhf(xp[2048 + j] + rr * (D2 + sbhh[2048 + j]));
            float hprev = (tau > 0) ? rbuf[bq * 1024 + j] : 0.f;
            float hnew = (1.f - zz) * nn + zz * hprev;
            wbuf[bq * 1024 + j] = hnew;
            sbi[(long)pos * 2048 + bq * 1024 + j] = hnew;
        }

        if (tau != 95) grid_barrier(bar_cnt, bar_gen, 128);
        float* tmp = wbuf; wbuf = rbuf; rbuf = tmp;
    }
}

// ---------------- sentence attention ----------------
__global__ __launch_bounds__(256) void sent_scores(
    const float* __restrict__ sbi, const float* __restrict__ sctx,
    const float* __restrict__ sctx_b, float* __restrict__ scores)
{
    __shared__ float red[4];
    int s = blockIdx.x, t = threadIdx.x, c = t * 8;
    const float* row = sbi + (long)s * 2048 + c;
    float p = 0.f;
#pragma unroll
    for (int i = 0; i < 8; i++) p += row[i] * sctx[c + i];
    p += __shfl_xor(p, 32); p += __shfl_xor(p, 16); p += __shfl_xor(p, 8);
    p += __shfl_xor(p, 4);  p += __shfl_xor(p, 2);  p += __shfl_xor(p, 1);
    int lane = t & 63, w = t >> 6;
    if (lane == 0) red[w] = p;
    __syncthreads();
    if (t == 0) scores[s] = expf(red[0] + red[1] + red[2] + red[3] + sctx_b[0]);
}

__global__ __launch_bounds__(256) void doc_out(
    const float* __restrict__ sbi, const float* __restrict__ scores,
    float* __restrict__ out)
{
    int t = threadIdx.x, c = t * 8;
    float acc[8];
#pragma unroll
    for (int i = 0; i < 8; i++) acc[i] = 0.f;
    for (int s = 0; s < 96; s++) {
        float sc = scores[s];
        const float* row = sbi + (long)s * 2048 + c;
#pragma unroll
        for (int i = 0; i < 8; i++) acc[i] += sc * row[i];
    }
#pragma unroll
    for (int i = 0; i < 8; i++) out[c + i] = acc[i];
}

// ---------------- host ----------------
extern "C" void kernel_launch(void* const* d_in, const int* in_sizes, int n_in,
                              void* d_out, int out_size, void* d_ws, size_t ws_size,
                              hipStream_t stream)
{
    const int*   tokens    = (const int*)  d_in[0];
    const float* embedding = (const float*)d_in[1];
    const float* wWih = (const float*)d_in[2];
    const float* wWhh = (const float*)d_in[3];
    const float* wbih = (const float*)d_in[4];
    const float* wbhh = (const float*)d_in[5];
    const float* sWih = (const float*)d_in[6];
    const float* sWhh = (const float*)d_in[7];
    const float* sbih = (const float*)d_in[8];
    const float* sbhh = (const float*)d_in[9];
    const float* wctxw = (const float*)d_in[10];
    const float* wctxb = (const float*)d_in[11];
    const float* sctxw = (const float*)d_in[12];
    const float* sctxb = (const float*)d_in[13];
    float* out = (float*)d_out;

    char* p = (char*)d_ws;
    auto alloc = [&](size_t bytes) -> char* {
        char* r = p;
        p += (bytes + 255) & ~(size_t)255;
        return r;
    };
    unsigned short* WihHi  = (unsigned short*)alloc(3072l * 1024 * 2);
    unsigned short* WihLo  = (unsigned short*)alloc(3072l * 1024 * 2);
    unsigned short* WhhHi  = (unsigned short*)alloc(3072l * 1024 * 2);
    unsigned short* WhhLo  = (unsigned short*)alloc(3072l * 1024 * 2);
    unsigned short* sWihHi = (unsigned short*)alloc(3072l * 2048 * 2);
    unsigned short* sWihLo = (unsigned short*)alloc(3072l * 2048 * 2);
    float* xWt       = (float*)alloc(9216l * 3072 * 4);   // [pos][s][3072]
    float* bi        = (float*)alloc(9216l * 2048 * 4);
    unsigned short* hAhi = (unsigned short*)alloc(192l * 1024 * 2);
    unsigned short* hAlo = (unsigned short*)alloc(192l * 1024 * 2);
    unsigned short* hBhi = (unsigned short*)alloc(192l * 1024 * 2);
    unsigned short* hBlo = (unsigned short*)alloc(192l * 1024 * 2);
    float* sent_vecs = (float*)alloc(96l * 2048 * 4);
    float* xWs       = (float*)alloc(96l * 3072 * 4);
    float* hsA       = (float*)alloc(2l * 1024 * 4);
    float* hsB       = (float*)alloc(2l * 1024 * 4);
    float* sbi       = (float*)alloc(96l * 2048 * 4);
    float* scores    = (float*)alloc(512);
    float* wsc       = (float*)alloc(9216l * 4);
    unsigned* barbuf = (unsigned*)alloc(256);
    (void)ws_size; (void)in_sizes; (void)n_in; (void)out_size;

    hipMemsetAsync(barbuf, 0, 256, stream);
    hipMemsetAsync(hBhi, 0, 192l * 1024 * 2, stream);
    hipMemsetAsync(hBlo, 0, 192l * 1024 * 2, stream);

    split_f32<<<1024, 256, 0, stream>>>(wWih, WihHi, WihLo, 3072 * 1024);
    split_f32<<<1024, 256, 0, stream>>>(wWhh, WhhHi, WhhLo, 3072 * 1024);
    split_f32<<<1024, 256, 0, stream>>>(sWih, sWihHi, sWihLo, 3072 * 2048);

    // word input projection, stored transposed: xWt[pos][s][3072]
    gemm_split<<<dim3(144, 24), 256, 0, stream>>>(
        embedding, tokens, WihHi, WihLo, wbih, xWt, 9216, 3072, 1024, 1);

    // persistent word bi-GRU (96 steps internally)
    word_rnn<<<256, 384, 0, stream>>>(
        WhhHi, WhhLo, hAhi, hAlo, hBhi, hBlo, xWt, wbhh, bi,
        barbuf + 0, barbuf + 16);

    // word attention
    wscore<<<2304, 256, 0, stream>>>(bi, wctxw, wctxb, wsc);
    wsum<<<dim3(96, 8), 256, 0, stream>>>(bi, wsc, sent_vecs);

    // sentence input projection: xWs[pos][3072]
    gemm_split<<<dim3(2, 24), 256, 0, stream>>>(
        sent_vecs, nullptr, sWihHi, sWihLo, sbih, xWs, 96, 3072, 2048, 0);

    // persistent sentence bi-GRU
    sent_rnn<<<128, 256, 0, stream>>>(
        sWhh, xWs, sbhh, hsA, hsB, sbi, barbuf + 32, barbuf + 48);

    sent_scores<<<96, 256, 0, stream>>>(sbi, sctxw, sctxb, scores);
    doc_out<<<1, 256, 0, stream>>>(sbi, scores, out);
}

// Round 5
// 4498.970 us; speedup vs baseline: 1.2299x; 1.1804x over previous
//
#include <hip/hip_runtime.h>
#include <hip/hip_bf16.h>
#include <math.h>

// HAN: word bi-GRU + attention -> sentence bi-GRU + attention -> doc vector.
// Split-bf16 (hi+lo) MFMA for big GEMMs; f32 vector math for gates/attention.
// R5: grid barrier with RELAXED spin (no per-poll L2 invalidation storm);
//     word_rnn K-loop barrier-free: A direct global->reg, static 4-deep
//     pipeline, f32 h state with in-register trunc split, ping-pong accs.

typedef __attribute__((ext_vector_type(8))) short short8;
typedef __attribute__((ext_vector_type(4))) float f32x4;

__device__ __forceinline__ unsigned short f2bf(float f) {
    unsigned int u = __float_as_uint(f);
    u += 0x7fff + ((u >> 16) & 1);   // RNE
    return (unsigned short)(u >> 16);
}
__device__ __forceinline__ float bf2f(unsigned short u) {
    return __uint_as_float(((unsigned int)u) << 16);
}
__device__ __forceinline__ float sigmoidf_(float x) { return 1.f / (1.f + expf(-x)); }

__device__ __forceinline__ f32x4 mfma16(short8 a, short8 b, f32x4 c) {
    return __builtin_amdgcn_mfma_f32_16x16x32_bf16(a, b, c, 0, 0, 0);
}

// trunc-split 8 f32 -> hi/lo bf16 short8 (pure bit ops, ~24 VALU)
__device__ __forceinline__ void split_win(f32x4 a, f32x4 b, short8* hv, short8* lv) {
    union { short8 s; unsigned u[4]; } H, L;
#pragma unroll
    for (int d = 0; d < 4; d++) {
        float f0 = (d < 2) ? a[2 * d] : b[2 * d - 4];
        float f1 = (d < 2) ? a[2 * d + 1] : b[2 * d - 3];
        unsigned u0 = __float_as_uint(f0), u1 = __float_as_uint(f1);
        H.u[d] = (u1 & 0xffff0000u) | (u0 >> 16);
        float l0 = f0 - __uint_as_float(u0 & 0xffff0000u);
        float l1 = f1 - __uint_as_float(u1 & 0xffff0000u);
        L.u[d] = (__float_as_uint(l1) & 0xffff0000u) | (__float_as_uint(l0) >> 16);
    }
    *hv = H.s; *lv = L.s;
}

// Grid barrier: RELEASE arrival, RELAXED spin (agent atomics bypass L2, no
// buffer_inv per poll), single ACQUIRE (add-0 RMW) after wake.
__device__ __forceinline__ void grid_barrier(unsigned* cnt, unsigned* gen, unsigned nblk) {
    __syncthreads();
    if (threadIdx.x == 0) {
        unsigned g = __hip_atomic_load(gen, __ATOMIC_RELAXED, __HIP_MEMORY_SCOPE_AGENT);
        unsigned old = __hip_atomic_fetch_add(cnt, 1u, __ATOMIC_RELEASE, __HIP_MEMORY_SCOPE_AGENT);
        if (old == nblk - 1u) {
            (void)__hip_atomic_fetch_add(cnt, 0u, __ATOMIC_ACQUIRE, __HIP_MEMORY_SCOPE_AGENT);
            __hip_atomic_store(cnt, 0u, __ATOMIC_RELAXED, __HIP_MEMORY_SCOPE_AGENT);
            __hip_atomic_store(gen, g + 1u, __ATOMIC_RELEASE, __HIP_MEMORY_SCOPE_AGENT);
        } else {
            int spins = 0;
            while (__hip_atomic_load(gen, __ATOMIC_RELAXED, __HIP_MEMORY_SCOPE_AGENT) == g) {
                __builtin_amdgcn_s_sleep(2);
                if (++spins == 2048) {   // safety: force visibility if relaxed ever caches
                    spins = 0;
                    (void)__hip_atomic_fetch_add(cnt, 0u, __ATOMIC_ACQUIRE, __HIP_MEMORY_SCOPE_AGENT);
                }
            }
            (void)__hip_atomic_fetch_add(cnt, 0u, __ATOMIC_ACQUIRE, __HIP_MEMORY_SCOPE_AGENT);
        }
    }
    __syncthreads();
}

// ---------------- split f32 -> (hi,lo) bf16 ----------------
__global__ __launch_bounds__(256) void split_f32(const float* __restrict__ src,
                                                 unsigned short* __restrict__ hi,
                                                 unsigned short* __restrict__ lo, int n) {
    int i = blockIdx.x * blockDim.x + threadIdx.x;
    int stride = gridDim.x * blockDim.x;
    for (; i < n; i += stride) {
        float v = src[i];
        unsigned short h = f2bf(v);
        hi[i] = h;
        lo[i] = f2bf(v - bf2f(h));
    }
}

// ---------------- split-bf16 MFMA GEMM (NT) ----------------
__global__ __launch_bounds__(256) void gemm_split(
    const float* __restrict__ A, const int* __restrict__ tokens,
    const unsigned short* __restrict__ Bhi, const unsigned short* __restrict__ Blo,
    const float* __restrict__ bias, float* __restrict__ C,
    int M, int N, int K, int tr96)
{
    __shared__ unsigned short Ah[64][40], Al[64][40];
    __shared__ unsigned short Bh[128][40], Bl[128][40];

    int t = threadIdx.x;
    int m0 = blockIdx.x * 64, n0 = blockIdx.y * 128;
    int wave = t >> 6, lane = t & 63;
    int wm = wave >> 1, wn = wave & 1;
    int kg = lane >> 4, r16 = lane & 15;

    f32x4 acc[2][4];
#pragma unroll
    for (int i = 0; i < 2; i++)
#pragma unroll
        for (int j = 0; j < 4; j++)
#pragma unroll
            for (int q = 0; q < 4; q++) acc[i][j][q] = 0.f;

    int ar = t >> 2, ac8 = (t & 3) * 8;
    long arow = -1;
    if (m0 + ar < M) arow = tokens ? (long)tokens[m0 + ar] : (long)(m0 + ar);

    for (int kt = 0; kt < K; kt += 32) {
        {
            short8 hv, lv;
            if (arow >= 0) {
                const float* ap = A + arow * (long)K + kt + ac8;
                f32x4 u0 = *(const f32x4*)ap;
                f32x4 u1 = *(const f32x4*)(ap + 4);
#pragma unroll
                for (int i = 0; i < 8; i++) {
                    float x = (i < 4) ? u0[i] : u1[i - 4];
                    unsigned short hb = f2bf(x);
                    hv[i] = (short)hb;
                    lv[i] = (short)f2bf(x - bf2f(hb));
                }
            } else {
#pragma unroll
                for (int i = 0; i < 8; i++) { hv[i] = 0; lv[i] = 0; }
            }
            *(short8*)&Ah[ar][ac8] = hv;
            *(short8*)&Al[ar][ac8] = lv;
        }
#pragma unroll
        for (int i = 0; i < 2; i++) {
            int idx = t + i * 256;
            int br = idx >> 2, bc8 = (idx & 3) * 8;
            long go = (long)(n0 + br) * K + kt + bc8;
            *(short8*)&Bh[br][bc8] = *(const short8*)(Bhi + go);
            *(short8*)&Bl[br][bc8] = *(const short8*)(Blo + go);
        }
        __syncthreads();

        short8 afh[2], afl[2], bfh[4], bfl[4];
#pragma unroll
        for (int m16 = 0; m16 < 2; m16++) {
            afh[m16] = *(short8*)&Ah[wm * 32 + m16 * 16 + r16][kg * 8];
            afl[m16] = *(short8*)&Al[wm * 32 + m16 * 16 + r16][kg * 8];
        }
#pragma unroll
        for (int n16 = 0; n16 < 4; n16++) {
            bfh[n16] = *(short8*)&Bh[wn * 64 + n16 * 16 + r16][kg * 8];
            bfl[n16] = *(short8*)&Bl[wn * 64 + n16 * 16 + r16][kg * 8];
        }
#pragma unroll
        for (int m16 = 0; m16 < 2; m16++)
#pragma unroll
            for (int n16 = 0; n16 < 4; n16++) {
                acc[m16][n16] = mfma16(afh[m16], bfh[n16], acc[m16][n16]);
                acc[m16][n16] = mfma16(afh[m16], bfl[n16], acc[m16][n16]);
                acc[m16][n16] = mfma16(afl[m16], bfh[n16], acc[m16][n16]);
            }
        __syncthreads();
    }

#pragma unroll
    for (int m16 = 0; m16 < 2; m16++)
#pragma unroll
        for (int n16 = 0; n16 < 4; n16++)
#pragma unroll
            for (int q = 0; q < 4; q++) {
                int row = m0 + wm * 32 + m16 * 16 + kg * 4 + q;
                int col = n0 + wn * 64 + n16 * 16 + r16;
                if (row < M) {
                    long crow = tr96 ? (long)((row % 96) * 96 + row / 96) : (long)row;
                    C[crow * N + col] = acc[m16][n16][q] + bias[col];
                }
            }
}

// ---------------- persistent word bi-GRU v4 ----------------
// 256 blocks x 384 thr (6 waves). block: msplit = blk>>7 (96 rows), 8-j slice.
// Whh hi+lo LDS-resident [arr][kg][brow 0-23][8] (96KB). h state f32 [192][1024].
// K-loop: A direct global->reg (4-deep static pipeline), NO syncthreads.
__global__ __launch_bounds__(384) void word_rnn(
    const unsigned short* __restrict__ Whi, const unsigned short* __restrict__ Wlo,
    float* __restrict__ hA, float* __restrict__ hB,
    const float* __restrict__ xWt,   // [96 pos][96 s][3072]
    const float* __restrict__ bhh, float* __restrict__ bi,
    unsigned* bar_cnt, unsigned* bar_gen)
{
    __shared__ unsigned short Wh[2][128][24][8];    // 96KB

    int t = threadIdx.x;
    int blk = blockIdx.x;
    int msplit = blk >> 7;
    int j0 = (blk & 127) * 8;
    int w = t >> 6, lane = t & 63, kg4 = lane >> 4, r16 = lane & 15;

    for (int i = t; i < 4096; i += 384) {
        int kg = i >> 5, br = i & 31;
        if (br < 24) {
            long src = (long)((br >> 3) * 1024 + j0 + (br & 7)) * 1024 + kg * 8;
            *(short8*)&Wh[0][kg][br][0] = *(const short8*)(Whi + src);
            *(short8*)&Wh[1][kg][br][0] = *(const short8*)(Wlo + src);
        }
    }
    __syncthreads();

    const float* rbuf = hB;
    float* wbuf = hA;

    int jj = r16 & 7;
    int j = j0 + jj;
    float b_r = bhh[j], b_z = bhh[1024 + j], b_n = bhh[2048 + j];
    long abase = (long)(msplit * 96 + w * 16 + r16) * 1024 + kg4 * 8;

    f32x4 A0a, A0b, A1a, A1b, A2a, A2b, A3a, A3b;

#define LDW(Xa, Xb, ki)                                                   \
    do {                                                                  \
        const float* ap = rbuf + abase + (ki) * 32;                       \
        Xa = *(const f32x4*)ap;                                           \
        Xb = *(const f32x4*)(ap + 4);                                     \
    } while (0)

#define DOW(Xa, Xb, ki, P)                                                \
    do {                                                                  \
        short8 ah, al;                                                    \
        split_win(Xa, Xb, &ah, &al);                                      \
        int kgB = (ki) * 4 + kg4;                                         \
        short8 b0h = *(short8*)&Wh[0][kgB][r16][0];                       \
        short8 b0l = *(short8*)&Wh[1][kgB][r16][0];                       \
        short8 b1h = *(short8*)&Wh[0][kgB][16 + jj][0];                   \
        short8 b1l = *(short8*)&Wh[1][kgB][16 + jj][0];                   \
        acc0##P = mfma16(ah, b0h, acc0##P);                               \
        acc0##P = mfma16(ah, b0l, acc0##P);                               \
        acc0##P = mfma16(al, b0h, acc0##P);                               \
        acc1##P = mfma16(ah, b1h, acc1##P);                               \
        acc1##P = mfma16(ah, b1l, acc1##P);                               \
        acc1##P = mfma16(al, b1h, acc1##P);                               \
    } while (0)

    for (int tau = 0; tau < 96; tau++) {
        int pos = msplit ? (95 - tau) : tau;

        f32x4 acc0A, acc0B, acc1A, acc1B;
#pragma unroll
        for (int q = 0; q < 4; q++) { acc0A[q] = 0.f; acc0B[q] = 0.f; acc1A[q] = 0.f; acc1B[q] = 0.f; }

        // prime the pipeline
        LDW(A0a, A0b, 0); LDW(A1a, A1b, 1); LDW(A2a, A2b, 2); LDW(A3a, A3b, 3);

        // epilogue operands: issue now, retire under the K-loop
        float xwv[4][3];
        float hpv[4];
#pragma unroll
        for (int q = 0; q < 4; q++) {
            if (r16 < 8) {
                int hloc = w * 16 + kg4 * 4 + q;
                const float* xp = xWt + ((long)pos * 96 + hloc) * 3072 + j;
                xwv[q][0] = xp[0];
                xwv[q][1] = xp[1024];
                xwv[q][2] = xp[2048];
                hpv[q] = rbuf[(long)(msplit * 96 + hloc) * 1024 + j];
            } else {
                xwv[q][0] = xwv[q][1] = xwv[q][2] = 0.f;
                hpv[q] = 0.f;
            }
        }

#pragma unroll
        for (int kb = 0; kb < 32; kb += 4) {
            DOW(A0a, A0b, kb + 0, A); if (kb + 4 < 32) LDW(A0a, A0b, kb + 4);
            DOW(A1a, A1b, kb + 1, B); if (kb + 5 < 32) LDW(A1a, A1b, kb + 5);
            DOW(A2a, A2b, kb + 2, A); if (kb + 6 < 32) LDW(A2a, A2b, kb + 6);
            DOW(A3a, A3b, kb + 3, B); if (kb + 7 < 32) LDW(A3a, A3b, kb + 7);
        }

        // epilogue: acc0 = {g0 (r16<8), g1 (r16>=8)}, acc1 = g2
#pragma unroll
        for (int q = 0; q < 4; q++) {
            float g0 = acc0A[q] + acc0B[q];
            float g1 = __shfl_xor(g0, 8);
            float g2 = acc1A[q] + acc1B[q];
            if (r16 < 8) {
                int hloc = w * 16 + kg4 * 4 + q;
                float rr = sigmoidf_(xwv[q][0] + g0 + b_r);
                float zz = sigmoidf_(xwv[q][1] + g1 + b_z);
                float nn = tanhf(xwv[q][2] + rr * (g2 + b_n));
                float hnew = (1.f - zz) * nn + zz * hpv[q];
                wbuf[(long)(msplit * 96 + hloc) * 1024 + j] = hnew;
                bi[((long)hloc * 96 + pos) * 2048 + msplit * 1024 + j] = hnew;
            }
        }

        if (tau != 95) grid_barrier(bar_cnt, bar_gen, 256);
        float* tmp = wbuf; wbuf = (float*)rbuf; rbuf = tmp;
    }
#undef LDW
#undef DOW
}

// ---------------- word attention ----------------
__global__ __launch_bounds__(256) void wscore(
    const float* __restrict__ bi, const float* __restrict__ wctx,
    const float* __restrict__ wctx_b, float* __restrict__ wsc)
{
    int tok = blockIdx.x * 4 + (threadIdx.x >> 6);
    int lane = threadIdx.x & 63;
    const float* row = bi + (long)tok * 2048 + lane * 32;
    const float* cp = wctx + lane * 32;
    float p = 0.f;
#pragma unroll
    for (int i = 0; i < 32; i += 4) {
        f32x4 v = *(const f32x4*)(row + i);
        f32x4 c = *(const f32x4*)(cp + i);
        p += v[0] * c[0] + v[1] * c[1] + v[2] * c[2] + v[3] * c[3];
    }
    p += __shfl_xor(p, 32); p += __shfl_xor(p, 16); p += __shfl_xor(p, 8);
    p += __shfl_xor(p, 4);  p += __shfl_xor(p, 2);  p += __shfl_xor(p, 1);
    if (lane == 0) wsc[tok] = expf(p + wctx_b[0]);
}

__global__ __launch_bounds__(256) void wsum(
    const float* __restrict__ bi, const float* __restrict__ wsc,
    float* __restrict__ sent_vecs)
{
    int s = blockIdx.x;
    int c = blockIdx.y * 256 + threadIdx.x;
    float acc = 0.f;
    for (int tk = 0; tk < 96; tk++)
        acc += wsc[s * 96 + tk] * bi[((long)s * 96 + tk) * 2048 + c];
    sent_vecs[(long)s * 2048 + c] = acc;
}

// ---------------- persistent sentence bi-GRU ----------------
__global__ __launch_bounds__(256) void sent_rnn(
    const float* __restrict__ sWhh, const float* __restrict__ xWs,
    const float* __restrict__ sbhh, float* __restrict__ hA, float* __restrict__ hB,
    float* __restrict__ sbi, unsigned* bar_cnt, unsigned* bar_gen)
{
    __shared__ float Wl[24 * 1028];
    __shared__ float hsh[2048];
    __shared__ float part[4][48];

    int t = threadIdx.x;
    int j0 = blockIdx.x * 8;
    int w = t >> 6, lane = t & 63;

    for (int i = t; i < 24 * 1024; i += 256) {
        int row = i >> 10, k = i & 1023;
        Wl[row * 1028 + k] = sWhh[(long)((row >> 3) * 1024 + j0 + (row & 7)) * 1024 + k];
    }

    float* rbuf = hB;
    float* wbuf = hA;

    for (int tau = 0; tau < 96; tau++) {
        __syncthreads();
        for (int i = t; i < 2048; i += 256) hsh[i] = (tau > 0) ? rbuf[i] : 0.f;
        __syncthreads();

        if (lane < 48) {
            int row = lane >> 1, bq = lane & 1;
            const float* wp = &Wl[row * 1028 + w * 256];
            const float* hp = &hsh[bq * 1024 + w * 256];
            float accd = 0.f;
            for (int k = 0; k < 256; k += 4) {
                f32x4 wv = *(const f32x4*)(wp + k);
                f32x4 hv = *(const f32x4*)(hp + k);
                accd += wv[0] * hv[0] + wv[1] * hv[1] + wv[2] * hv[2] + wv[3] * hv[3];
            }
            part[w][lane] = accd;
        }
        __syncthreads();

        if (t < 16) {
            int jl2 = t >> 1, bq = t & 1;
            int j = j0 + jl2;
            int pos = bq ? (95 - tau) : tau;
            const float* xp = xWs + (long)pos * 3072;
            int d0 = (0 * 8 + jl2) * 2 + bq;
            int d1 = (1 * 8 + jl2) * 2 + bq;
            int d2 = (2 * 8 + jl2) * 2 + bq;
            float D0 = part[0][d0] + part[1][d0] + part[2][d0] + part[3][d0];
            float D1 = part[0][d1] + part[1][d1] + part[2][d1] + part[3][d1];
            float D2 = part[0][d2] + part[1][d2] + part[2][d2] + part[3][d2];
            float rr = sigmoidf_(xp[j] + D0 + sbhh[j]);
            float zz = sigmoidf_(xp[1024 + j] + D1 + sbhh[1024 + j]);
            float nn = tanhf(xp[2048 + j] + rr * (D2 + sbhh[2048 + j]));
            float hprev = (tau > 0) ? rbuf[bq * 1024 + j] : 0.f;
            float hnew = (1.f - zz) * nn + zz * hprev;
            wbuf[bq * 1024 + j] = hnew;
            sbi[(long)pos * 2048 + bq * 1024 + j] = hnew;
        }

        if (tau != 95) grid_barrier(bar_cnt, bar_gen, 128);
        float* tmp = wbuf; wbuf = rbuf; rbuf = tmp;
    }
}

// ---------------- sentence attention ----------------
__global__ __launch_bounds__(256) void sent_scores(
    const float* __restrict__ sbi, const float* __restrict__ sctx,
    const float* __restrict__ sctx_b, float* __restrict__ scores)
{
    __shared__ float red[4];
    int s = blockIdx.x, t = threadIdx.x, c = t * 8;
    const float* row = sbi + (long)s * 2048 + c;
    float p = 0.f;
#pragma unroll
    for (int i = 0; i < 8; i++) p += row[i] * sctx[c + i];
    p += __shfl_xor(p, 32); p += __shfl_xor(p, 16); p += __shfl_xor(p, 8);
    p += __shfl_xor(p, 4);  p += __shfl_xor(p, 2);  p += __shfl_xor(p, 1);
    int lane = t & 63, w = t >> 6;
    if (lane == 0) red[w] = p;
    __syncthreads();
    if (t == 0) scores[s] = expf(red[0] + red[1] + red[2] + red[3] + sctx_b[0]);
}

__global__ __launch_bounds__(256) void doc_out(
    const float* __restrict__ sbi, const float* __restrict__ scores,
    float* __restrict__ out)
{
    int t = threadIdx.x, c = t * 8;
    float acc[8];
#pragma unroll
    for (int i = 0; i < 8; i++) acc[i] = 0.f;
    for (int s = 0; s < 96; s++) {
        float sc = scores[s];
        const float* row = sbi + (long)s * 2048 + c;
#pragma unroll
        for (int i = 0; i < 8; i++) acc[i] += sc * row[i];
    }
#pragma unroll
    for (int i = 0; i < 8; i++) out[c + i] = acc[i];
}

// ---------------- host ----------------
extern "C" void kernel_launch(void* const* d_in, const int* in_sizes, int n_in,
                              void* d_out, int out_size, void* d_ws, size_t ws_size,
                              hipStream_t stream)
{
    const int*   tokens    = (const int*)  d_in[0];
    const float* embedding = (const float*)d_in[1];
    const float* wWih = (const float*)d_in[2];
    const float* wWhh = (const float*)d_in[3];
    const float* wbih = (const float*)d_in[4];
    const float* wbhh = (const float*)d_in[5];
    const float* sWih = (const float*)d_in[6];
    const float* sWhh = (const float*)d_in[7];
    const float* sbih = (const float*)d_in[8];
    const float* sbhh = (const float*)d_in[9];
    const float* wctxw = (const float*)d_in[10];
    const float* wctxb = (const float*)d_in[11];
    const float* sctxw = (const float*)d_in[12];
    const float* sctxb = (const float*)d_in[13];
    float* out = (float*)d_out;

    char* p = (char*)d_ws;
    auto alloc = [&](size_t bytes) -> char* {
        char* r = p;
        p += (bytes + 255) & ~(size_t)255;
        return r;
    };
    unsigned short* WihHi  = (unsigned short*)alloc(3072l * 1024 * 2);
    unsigned short* WihLo  = (unsigned short*)alloc(3072l * 1024 * 2);
    unsigned short* WhhHi  = (unsigned short*)alloc(3072l * 1024 * 2);
    unsigned short* WhhLo  = (unsigned short*)alloc(3072l * 1024 * 2);
    unsigned short* sWihHi = (unsigned short*)alloc(3072l * 2048 * 2);
    unsigned short* sWihLo = (unsigned short*)alloc(3072l * 2048 * 2);
    float* xWt       = (float*)alloc(9216l * 3072 * 4);   // [pos][s][3072]
    float* bi        = (float*)alloc(9216l * 2048 * 4);
    float* hAf       = (float*)alloc(192l * 1024 * 4);
    float* hBf       = (float*)alloc(192l * 1024 * 4);
    float* sent_vecs = (float*)alloc(96l * 2048 * 4);
    float* xWs       = (float*)alloc(96l * 3072 * 4);
    float* hsA       = (float*)alloc(2l * 1024 * 4);
    float* hsB       = (float*)alloc(2l * 1024 * 4);
    float* sbi       = (float*)alloc(96l * 2048 * 4);
    float* scores    = (float*)alloc(512);
    float* wsc       = (float*)alloc(9216l * 4);
    unsigned* barbuf = (unsigned*)alloc(256);
    (void)ws_size; (void)in_sizes; (void)n_in; (void)out_size;

    hipMemsetAsync(barbuf, 0, 256, stream);
    hipMemsetAsync(hBf, 0, 192l * 1024 * 4, stream);

    split_f32<<<1024, 256, 0, stream>>>(wWih, WihHi, WihLo, 3072 * 1024);
    split_f32<<<1024, 256, 0, stream>>>(wWhh, WhhHi, WhhLo, 3072 * 1024);
    split_f32<<<1024, 256, 0, stream>>>(sWih, sWihHi, sWihLo, 3072 * 2048);

    // word input projection, stored transposed: xWt[pos][s][3072]
    gemm_split<<<dim3(144, 24), 256, 0, stream>>>(
        embedding, tokens, WihHi, WihLo, wbih, xWt, 9216, 3072, 1024, 1);

    // persistent word bi-GRU (96 steps internally)
    word_rnn<<<256, 384, 0, stream>>>(
        WhhHi, WhhLo, hAf, hBf, xWt, wbhh, bi, barbuf + 0, barbuf + 16);

    // word attention
    wscore<<<2304, 256, 0, stream>>>(bi, wctxw, wctxb, wsc);
    wsum<<<dim3(96, 8), 256, 0, stream>>>(bi, wsc, sent_vecs);

    // sentence input projection: xWs[pos][3072]
    gemm_split<<<dim3(2, 24), 256, 0, stream>>>(
        sent_vecs, nullptr, sWihHi, sWihLo, sbih, xWs, 96, 3072, 2048, 0);

    // persistent sentence bi-GRU
    sent_rnn<<<128, 256, 0, stream>>>(
        sWhh, xWs, sbhh, hsA, hsB, sbi, barbuf + 32, barbuf + 48);

    sent_scores<<<96, 256, 0, stream>>>(sbi, sctxw, sctxb, scores);
    doc_out<<<1, 256, 0, stream>>>(sbi, scores, out);
}

// Round 6
// 3788.501 us; speedup vs baseline: 1.4605x; 1.1875x over previous
//
#include <hip/hip_runtime.h>
#include <hip/hip_bf16.h>
#include <math.h>

// HAN: word bi-GRU + attention -> sentence bi-GRU + attention -> doc vector.
// Split-bf16 (hi+lo) MFMA for big GEMMs; f32 vector math for gates/attention.
// R6: persistent kernels abandoned (agent-scope barrier cache-ops = 20-60us/step
// of serialized L2 tag-walks). Back to launched per-step kernels with R5's
// latency-tolerant K-loop: A direct global->reg 4-deep pipeline, Whh slice
// LDS-filled per launch, f32 h ping-pong, in-register gate fusion.

typedef __attribute__((ext_vector_type(8))) short short8;
typedef __attribute__((ext_vector_type(4))) float f32x4;

__device__ __forceinline__ unsigned short f2bf(float f) {
    unsigned int u = __float_as_uint(f);
    u += 0x7fff + ((u >> 16) & 1);   // RNE
    return (unsigned short)(u >> 16);
}
__device__ __forceinline__ float bf2f(unsigned short u) {
    return __uint_as_float(((unsigned int)u) << 16);
}
__device__ __forceinline__ float sigmoidf_(float x) { return 1.f / (1.f + expf(-x)); }

__device__ __forceinline__ f32x4 mfma16(short8 a, short8 b, f32x4 c) {
    return __builtin_amdgcn_mfma_f32_16x16x32_bf16(a, b, c, 0, 0, 0);
}

// trunc-split 8 f32 -> hi/lo bf16 short8 (pure bit ops)
__device__ __forceinline__ void split_win(f32x4 a, f32x4 b, short8* hv, short8* lv) {
    union { short8 s; unsigned u[4]; } H, L;
#pragma unroll
    for (int d = 0; d < 4; d++) {
        float f0 = (d < 2) ? a[2 * d] : b[2 * d - 4];
        float f1 = (d < 2) ? a[2 * d + 1] : b[2 * d - 3];
        unsigned u0 = __float_as_uint(f0), u1 = __float_as_uint(f1);
        H.u[d] = (u1 & 0xffff0000u) | (u0 >> 16);
        float l0 = f0 - __uint_as_float(u0 & 0xffff0000u);
        float l1 = f1 - __uint_as_float(u1 & 0xffff0000u);
        L.u[d] = (__float_as_uint(l1) & 0xffff0000u) | (__float_as_uint(l0) >> 16);
    }
    *hv = H.s; *lv = L.s;
}

// ---------------- split f32 -> (hi,lo) bf16 ----------------
__global__ __launch_bounds__(256) void split_f32(const float* __restrict__ src,
                                                 unsigned short* __restrict__ hi,
                                                 unsigned short* __restrict__ lo, int n) {
    int i = blockIdx.x * blockDim.x + threadIdx.x;
    int stride = gridDim.x * blockDim.x;
    for (; i < n; i += stride) {
        float v = src[i];
        unsigned short h = f2bf(v);
        hi[i] = h;
        lo[i] = f2bf(v - bf2f(h));
    }
}

// ---------------- split-bf16 MFMA GEMM (NT) ----------------
__global__ __launch_bounds__(256) void gemm_split(
    const float* __restrict__ A, const int* __restrict__ tokens,
    const unsigned short* __restrict__ Bhi, const unsigned short* __restrict__ Blo,
    const float* __restrict__ bias, float* __restrict__ C,
    int M, int N, int K, int tr96)
{
    __shared__ unsigned short Ah[64][40], Al[64][40];
    __shared__ unsigned short Bh[128][40], Bl[128][40];

    int t = threadIdx.x;
    int m0 = blockIdx.x * 64, n0 = blockIdx.y * 128;
    int wave = t >> 6, lane = t & 63;
    int wm = wave >> 1, wn = wave & 1;
    int kg = lane >> 4, r16 = lane & 15;

    f32x4 acc[2][4];
#pragma unroll
    for (int i = 0; i < 2; i++)
#pragma unroll
        for (int j = 0; j < 4; j++)
#pragma unroll
            for (int q = 0; q < 4; q++) acc[i][j][q] = 0.f;

    int ar = t >> 2, ac8 = (t & 3) * 8;
    long arow = -1;
    if (m0 + ar < M) arow = tokens ? (long)tokens[m0 + ar] : (long)(m0 + ar);

    for (int kt = 0; kt < K; kt += 32) {
        {
            short8 hv, lv;
            if (arow >= 0) {
                const float* ap = A + arow * (long)K + kt + ac8;
                f32x4 u0 = *(const f32x4*)ap;
                f32x4 u1 = *(const f32x4*)(ap + 4);
#pragma unroll
                for (int i = 0; i < 8; i++) {
                    float x = (i < 4) ? u0[i] : u1[i - 4];
                    unsigned short hb = f2bf(x);
                    hv[i] = (short)hb;
                    lv[i] = (short)f2bf(x - bf2f(hb));
                }
            } else {
#pragma unroll
                for (int i = 0; i < 8; i++) { hv[i] = 0; lv[i] = 0; }
            }
            *(short8*)&Ah[ar][ac8] = hv;
            *(short8*)&Al[ar][ac8] = lv;
        }
#pragma unroll
        for (int i = 0; i < 2; i++) {
            int idx = t + i * 256;
            int br = idx >> 2, bc8 = (idx & 3) * 8;
            long go = (long)(n0 + br) * K + kt + bc8;
            *(short8*)&Bh[br][bc8] = *(const short8*)(Bhi + go);
            *(short8*)&Bl[br][bc8] = *(const short8*)(Blo + go);
        }
        __syncthreads();

        short8 afh[2], afl[2], bfh[4], bfl[4];
#pragma unroll
        for (int m16 = 0; m16 < 2; m16++) {
            afh[m16] = *(short8*)&Ah[wm * 32 + m16 * 16 + r16][kg * 8];
            afl[m16] = *(short8*)&Al[wm * 32 + m16 * 16 + r16][kg * 8];
        }
#pragma unroll
        for (int n16 = 0; n16 < 4; n16++) {
            bfh[n16] = *(short8*)&Bh[wn * 64 + n16 * 16 + r16][kg * 8];
            bfl[n16] = *(short8*)&Bl[wn * 64 + n16 * 16 + r16][kg * 8];
        }
#pragma unroll
        for (int m16 = 0; m16 < 2; m16++)
#pragma unroll
            for (int n16 = 0; n16 < 4; n16++) {
                acc[m16][n16] = mfma16(afh[m16], bfh[n16], acc[m16][n16]);
                acc[m16][n16] = mfma16(afh[m16], bfl[n16], acc[m16][n16]);
                acc[m16][n16] = mfma16(afl[m16], bfh[n16], acc[m16][n16]);
            }
        __syncthreads();
    }

#pragma unroll
    for (int m16 = 0; m16 < 2; m16++)
#pragma unroll
        for (int n16 = 0; n16 < 4; n16++)
#pragma unroll
            for (int q = 0; q < 4; q++) {
                int row = m0 + wm * 32 + m16 * 16 + kg * 4 + q;
                int col = n0 + wn * 64 + n16 * 16 + r16;
                if (row < M) {
                    long crow = tr96 ? (long)((row % 96) * 96 + row / 96) : (long)row;
                    C[crow * N + col] = acc[m16][n16][q] + bias[col];
                }
            }
}

// ---------------- word GRU step (launched; R5 K-loop) ----------------
// 256 blocks x 384 thr (6 waves). block: msplit = blk>>7 (96 rows), 8-j slice.
// Whh hi+lo LDS-filled per launch [arr][kg][brow 0-23][8] (96KB).
// K-loop: A direct global->reg (4-deep static pipeline), no syncthreads.
__global__ __launch_bounds__(384) void word_step3(
    const unsigned short* __restrict__ Whi, const unsigned short* __restrict__ Wlo,
    const float* __restrict__ rbuf, float* __restrict__ wbuf,
    const float* __restrict__ xWt,   // [96 pos][96 s][3072]
    const float* __restrict__ bhh, float* __restrict__ bi, int tau)
{
    __shared__ unsigned short Wh[2][128][24][8];    // 96KB

    int t = threadIdx.x;
    int blk = blockIdx.x;
    int msplit = blk >> 7;
    int j0 = (blk & 127) * 8;
    int w = t >> 6, lane = t & 63, kg4 = lane >> 4, r16 = lane & 15;

    // per-launch Whh slice fill
    for (int i = t; i < 4096; i += 384) {
        int kg = i >> 5, br = i & 31;
        if (br < 24) {
            long src = (long)((br >> 3) * 1024 + j0 + (br & 7)) * 1024 + kg * 8;
            *(short8*)&Wh[0][kg][br][0] = *(const short8*)(Whi + src);
            *(short8*)&Wh[1][kg][br][0] = *(const short8*)(Wlo + src);
        }
    }

    int jj = r16 & 7;
    int j = j0 + jj;
    float b_r = bhh[j], b_z = bhh[1024 + j], b_n = bhh[2048 + j];
    long abase = (long)(msplit * 96 + w * 16 + r16) * 1024 + kg4 * 8;
    int pos = msplit ? (95 - tau) : tau;

    f32x4 A0a, A0b, A1a, A1b, A2a, A2b, A3a, A3b;

#define LDW(Xa, Xb, ki)                                                   \
    do {                                                                  \
        const float* ap = rbuf + abase + (ki) * 32;                       \
        Xa = *(const f32x4*)ap;                                           \
        Xb = *(const f32x4*)(ap + 4);                                     \
    } while (0)

#define DOW(Xa, Xb, ki, P)                                                \
    do {                                                                  \
        short8 ah, al;                                                    \
        split_win(Xa, Xb, &ah, &al);                                      \
        int kgB = (ki) * 4 + kg4;                                         \
        short8 b0h = *(short8*)&Wh[0][kgB][r16][0];                       \
        short8 b0l = *(short8*)&Wh[1][kgB][r16][0];                       \
        short8 b1h = *(short8*)&Wh[0][kgB][16 + jj][0];                   \
        short8 b1l = *(short8*)&Wh[1][kgB][16 + jj][0];                   \
        acc0##P = mfma16(ah, b0h, acc0##P);                               \
        acc0##P = mfma16(ah, b0l, acc0##P);                               \
        acc0##P = mfma16(al, b0h, acc0##P);                               \
        acc1##P = mfma16(ah, b1h, acc1##P);                               \
        acc1##P = mfma16(ah, b1l, acc1##P);                               \
        acc1##P = mfma16(al, b1h, acc1##P);                               \
    } while (0)

    f32x4 acc0A, acc0B, acc1A, acc1B;
#pragma unroll
    for (int q = 0; q < 4; q++) { acc0A[q] = 0.f; acc0B[q] = 0.f; acc1A[q] = 0.f; acc1B[q] = 0.f; }

    // prime pipeline (overlaps with LDS fill; no dependence on it)
    LDW(A0a, A0b, 0); LDW(A1a, A1b, 1); LDW(A2a, A2b, 2); LDW(A3a, A3b, 3);

    // epilogue operands: issue now, retire under the K-loop
    float xwv[4][3];
    float hpv[4];
#pragma unroll
    for (int q = 0; q < 4; q++) {
        if (r16 < 8) {
            int hloc = w * 16 + kg4 * 4 + q;
            const float* xp = xWt + ((long)pos * 96 + hloc) * 3072 + j;
            xwv[q][0] = xp[0];
            xwv[q][1] = xp[1024];
            xwv[q][2] = xp[2048];
            hpv[q] = rbuf[(long)(msplit * 96 + hloc) * 1024 + j];
        } else {
            xwv[q][0] = xwv[q][1] = xwv[q][2] = 0.f;
            hpv[q] = 0.f;
        }
    }

    __syncthreads();   // Whh LDS fill complete

#pragma unroll
    for (int kb = 0; kb < 32; kb += 4) {
        DOW(A0a, A0b, kb + 0, A); if (kb + 4 < 32) LDW(A0a, A0b, kb + 4);
        DOW(A1a, A1b, kb + 1, B); if (kb + 5 < 32) LDW(A1a, A1b, kb + 5);
        DOW(A2a, A2b, kb + 2, A); if (kb + 6 < 32) LDW(A2a, A2b, kb + 6);
        DOW(A3a, A3b, kb + 3, B); if (kb + 7 < 32) LDW(A3a, A3b, kb + 7);
    }

    // epilogue: acc0 = {g0 (r16<8), g1 (r16>=8)}, acc1 = g2
#pragma unroll
    for (int q = 0; q < 4; q++) {
        float g0 = acc0A[q] + acc0B[q];
        float g1 = __shfl_xor(g0, 8);
        float g2 = acc1A[q] + acc1B[q];
        if (r16 < 8) {
            int hloc = w * 16 + kg4 * 4 + q;
            float rr = sigmoidf_(xwv[q][0] + g0 + b_r);
            float zz = sigmoidf_(xwv[q][1] + g1 + b_z);
            float nn = tanhf(xwv[q][2] + rr * (g2 + b_n));
            float hnew = (1.f - zz) * nn + zz * hpv[q];
            wbuf[(long)(msplit * 96 + hloc) * 1024 + j] = hnew;
            bi[((long)hloc * 96 + pos) * 2048 + msplit * 1024 + j] = hnew;
        }
    }
#undef LDW
#undef DOW
}

// ---------------- word attention ----------------
__global__ __launch_bounds__(256) void wscore(
    const float* __restrict__ bi, const float* __restrict__ wctx,
    const float* __restrict__ wctx_b, float* __restrict__ wsc)
{
    int tok = blockIdx.x * 4 + (threadIdx.x >> 6);
    int lane = threadIdx.x & 63;
    const float* row = bi + (long)tok * 2048 + lane * 32;
    const float* cp = wctx + lane * 32;
    float p = 0.f;
#pragma unroll
    for (int i = 0; i < 32; i += 4) {
        f32x4 v = *(const f32x4*)(row + i);
        f32x4 c = *(const f32x4*)(cp + i);
        p += v[0] * c[0] + v[1] * c[1] + v[2] * c[2] + v[3] * c[3];
    }
    p += __shfl_xor(p, 32); p += __shfl_xor(p, 16); p += __shfl_xor(p, 8);
    p += __shfl_xor(p, 4);  p += __shfl_xor(p, 2);  p += __shfl_xor(p, 1);
    if (lane == 0) wsc[tok] = expf(p + wctx_b[0]);
}

__global__ __launch_bounds__(256) void wsum(
    const float* __restrict__ bi, const float* __restrict__ wsc,
    float* __restrict__ sent_vecs)
{
    int s = blockIdx.x;
    int c = blockIdx.y * 256 + threadIdx.x;
    float acc = 0.f;
    for (int tk = 0; tk < 96; tk++)
        acc += wsc[s * 96 + tk] * bi[((long)s * 96 + tk) * 2048 + c];
    sent_vecs[(long)s * 2048 + c] = acc;
}

// ---------------- sentence GRU step (launched; f32 vector; batch 2) ----------
__global__ __launch_bounds__(384) void sent_step(
    const float* __restrict__ Whh, const float* __restrict__ xWs,
    const float* __restrict__ sbhh, const float* __restrict__ hs_in,
    float* __restrict__ hs_out, float* __restrict__ sbi, int tau)
{
    __shared__ float sh[2][1024];
    __shared__ float gdot[3][16][2];
    int t = threadIdx.x, j0 = blockIdx.x * 16;

    for (int idx = t; idx < 2048; idx += 384)
        sh[idx >> 10][idx & 1023] = (tau > 0) ? hs_in[idx] : 0.f;
    __syncthreads();

    {
        int d = t >> 2, kq = t & 3;     // 96 dots x 4 k-quarters
        int rr = d >> 1, bq = d & 1;
        int gg = rr >> 4, jl = rr & 15;
        int wrow = gg * 1024 + j0 + jl;
        const float* wp = Whh + (long)wrow * 1024 + kq * 256;
        const float* hp = &sh[bq][kq * 256];
        float acc = 0.f;
        for (int k = 0; k < 256; k += 4) {
            f32x4 wv = *(const f32x4*)(wp + k);
            f32x4 hv = *(const f32x4*)(hp + k);
            acc += wv[0] * hv[0] + wv[1] * hv[1] + wv[2] * hv[2] + wv[3] * hv[3];
        }
        acc += __shfl_xor(acc, 1);
        acc += __shfl_xor(acc, 2);
        if (kq == 0) gdot[gg][jl][bq] = acc;
    }
    __syncthreads();

    if (t < 32) {
        int jl = t >> 1, bq = t & 1;
        int j = j0 + jl;
        int pos = bq ? (95 - tau) : tau;
        const float* xp = xWs + (long)pos * 3072;
        float r = sigmoidf_(xp[j] + gdot[0][jl][bq] + sbhh[j]);
        float z = sigmoidf_(xp[1024 + j] + gdot[1][jl][bq] + sbhh[1024 + j]);
        float n = tanhf(xp[2048 + j] + r * (gdot[2][jl][bq] + sbhh[2048 + j]));
        float hprev = (tau > 0) ? hs_in[bq * 1024 + j] : 0.f;
        float hnew = (1.f - z) * n + z * hprev;
        hs_out[bq * 1024 + j] = hnew;
        sbi[(long)pos * 2048 + bq * 1024 + j] = hnew;
    }
}

// ---------------- sentence attention ----------------
__global__ __launch_bounds__(256) void sent_scores(
    const float* __restrict__ sbi, const float* __restrict__ sctx,
    const float* __restrict__ sctx_b, float* __restrict__ scores)
{
    __shared__ float red[4];
    int s = blockIdx.x, t = threadIdx.x, c = t * 8;
    const float* row = sbi + (long)s * 2048 + c;
    float p = 0.f;
#pragma unroll
    for (int i = 0; i < 8; i++) p += row[i] * sctx[c + i];
    p += __shfl_xor(p, 32); p += __shfl_xor(p, 16); p += __shfl_xor(p, 8);
    p += __shfl_xor(p, 4);  p += __shfl_xor(p, 2);  p += __shfl_xor(p, 1);
    int lane = t & 63, w = t >> 6;
    if (lane == 0) red[w] = p;
    __syncthreads();
    if (t == 0) scores[s] = expf(red[0] + red[1] + red[2] + red[3] + sctx_b[0]);
}

__global__ __launch_bounds__(256) void doc_out(
    const float* __restrict__ sbi, const float* __restrict__ scores,
    float* __restrict__ out)
{
    int t = threadIdx.x, c = t * 8;
    float acc[8];
#pragma unroll
    for (int i = 0; i < 8; i++) acc[i] = 0.f;
    for (int s = 0; s < 96; s++) {
        float sc = scores[s];
        const float* row = sbi + (long)s * 2048 + c;
#pragma unroll
        for (int i = 0; i < 8; i++) acc[i] += sc * row[i];
    }
#pragma unroll
    for (int i = 0; i < 8; i++) out[c + i] = acc[i];
}

// ---------------- host ----------------
extern "C" void kernel_launch(void* const* d_in, const int* in_sizes, int n_in,
                              void* d_out, int out_size, void* d_ws, size_t ws_size,
                              hipStream_t stream)
{
    const int*   tokens    = (const int*)  d_in[0];
    const float* embedding = (const float*)d_in[1];
    const float* wWih = (const float*)d_in[2];
    const float* wWhh = (const float*)d_in[3];
    const float* wbih = (const float*)d_in[4];
    const float* wbhh = (const float*)d_in[5];
    const float* sWih = (const float*)d_in[6];
    const float* sWhh = (const float*)d_in[7];
    const float* sbih = (const float*)d_in[8];
    const float* sbhh = (const float*)d_in[9];
    const float* wctxw = (const float*)d_in[10];
    const float* wctxb = (const float*)d_in[11];
    const float* sctxw = (const float*)d_in[12];
    const float* sctxb = (const float*)d_in[13];
    float* out = (float*)d_out;

    char* p = (char*)d_ws;
    auto alloc = [&](size_t bytes) -> char* {
        char* r = p;
        p += (bytes + 255) & ~(size_t)255;
        return r;
    };
    unsigned short* WihHi  = (unsigned short*)alloc(3072l * 1024 * 2);
    unsigned short* WihLo  = (unsigned short*)alloc(3072l * 1024 * 2);
    unsigned short* WhhHi  = (unsigned short*)alloc(3072l * 1024 * 2);
    unsigned short* WhhLo  = (unsigned short*)alloc(3072l * 1024 * 2);
    unsigned short* sWihHi = (unsigned short*)alloc(3072l * 2048 * 2);
    unsigned short* sWihLo = (unsigned short*)alloc(3072l * 2048 * 2);
    float* xWt       = (float*)alloc(9216l * 3072 * 4);   // [pos][s][3072]
    float* bi        = (float*)alloc(9216l * 2048 * 4);
    float* hAf       = (float*)alloc(192l * 1024 * 4);
    float* hBf       = (float*)alloc(192l * 1024 * 4);
    float* sent_vecs = (float*)alloc(96l * 2048 * 4);
    float* xWs       = (float*)alloc(96l * 3072 * 4);
    float* hsA       = (float*)alloc(2l * 1024 * 4);
    float* hsB       = (float*)alloc(2l * 1024 * 4);
    float* sbi       = (float*)alloc(96l * 2048 * 4);
    float* scores    = (float*)alloc(512);
    float* wsc       = (float*)alloc(9216l * 4);
    (void)ws_size; (void)in_sizes; (void)n_in; (void)out_size;

    hipMemsetAsync(hBf, 0, 192l * 1024 * 4, stream);

    split_f32<<<1024, 256, 0, stream>>>(wWih, WihHi, WihLo, 3072 * 1024);
    split_f32<<<1024, 256, 0, stream>>>(wWhh, WhhHi, WhhLo, 3072 * 1024);
    split_f32<<<1024, 256, 0, stream>>>(sWih, sWihHi, sWihLo, 3072 * 2048);

    // word input projection, stored transposed: xWt[pos][s][3072]
    gemm_split<<<dim3(144, 24), 256, 0, stream>>>(
        embedding, tokens, WihHi, WihLo, wbih, xWt, 9216, 3072, 1024, 1);

    // word bi-GRU, 96 launched steps, h f32 ping-pong
    for (int tau = 0; tau < 96; tau++) {
        const float* rb; float* wb;
        if (tau & 1) { rb = hAf; wb = hBf; }
        else         { rb = hBf; wb = hAf; }
        word_step3<<<256, 384, 0, stream>>>(
            WhhHi, WhhLo, rb, wb, xWt, wbhh, bi, tau);
    }

    // word attention
    wscore<<<2304, 256, 0, stream>>>(bi, wctxw, wctxb, wsc);
    wsum<<<dim3(96, 8), 256, 0, stream>>>(bi, wsc, sent_vecs);

    // sentence input projection: xWs[pos][3072]
    gemm_split<<<dim3(2, 24), 256, 0, stream>>>(
        sent_vecs, nullptr, sWihHi, sWihLo, sbih, xWs, 96, 3072, 2048, 0);

    // sentence bi-GRU, 96 launched steps
    for (int tau = 0; tau < 96; tau++) {
        const float* hin; float* hout;
        if (tau & 1) { hin = hsA; hout = hsB; }
        else         { hin = hsB; hout = hsA; }
        sent_step<<<64, 384, 0, stream>>>(sWhh, xWs, sbhh, hin, hout, sbi, tau);
    }

    sent_scores<<<96, 256, 0, stream>>>(sbi, sctxw, sctxb, scores);
    doc_out<<<1, 256, 0, stream>>>(sbi, scores, out);
}

// Round 7
// 3602.336 us; speedup vs baseline: 1.5360x; 1.0517x over previous
//
#include <hip/hip_runtime.h>
#include <hip/hip_bf16.h>
#include <math.h>

// HAN: word bi-GRU + attention -> sentence bi-GRU + attention -> doc vector.
// Split-bf16 (hi+lo) MFMA for big GEMMs; f32 vector math for gates/attention.
// R7: persistent RNN loops with ZERO cache maintenance:
//  - h state lives in bi/sbi rows (fresh address per step per direction)
//  - h writes: relaxed agent-scope atomic stores (IF-direct, bypass L1/L2)
//  - h reads: normal cached loads (first-touch per step -> L2 pulls IF truth,
//    then serves the 128x intra-XCD redundancy at L2 bandwidth)
//  - barrier: monotonic hierarchical relaxed counters, no acquire/release,
//    no buffer_inv/wb -> Whh & xWt stay L2-resident across all 96 steps.

typedef __attribute__((ext_vector_type(8))) short short8;
typedef __attribute__((ext_vector_type(4))) float f32x4;

__device__ __forceinline__ unsigned short f2bf(float f) {
    unsigned int u = __float_as_uint(f);
    u += 0x7fff + ((u >> 16) & 1);   // RNE
    return (unsigned short)(u >> 16);
}
__device__ __forceinline__ float bf2f(unsigned short u) {
    return __uint_as_float(((unsigned int)u) << 16);
}
__device__ __forceinline__ float sigmoidf_(float x) { return 1.f / (1.f + expf(-x)); }

__device__ __forceinline__ f32x4 mfma16(short8 a, short8 b, f32x4 c) {
    return __builtin_amdgcn_mfma_f32_16x16x32_bf16(a, b, c, 0, 0, 0);
}

// trunc-split 8 f32 -> hi/lo bf16 short8 (pure bit ops)
__device__ __forceinline__ void split_win(f32x4 a, f32x4 b, short8* hv, short8* lv) {
    union { short8 s; unsigned u[4]; } H, L;
#pragma unroll
    for (int d = 0; d < 4; d++) {
        float f0 = (d < 2) ? a[2 * d] : b[2 * d - 4];
        float f1 = (d < 2) ? a[2 * d + 1] : b[2 * d - 3];
        unsigned u0 = __float_as_uint(f0), u1 = __float_as_uint(f1);
        H.u[d] = (u1 & 0xffff0000u) | (u0 >> 16);
        float l0 = f0 - __uint_as_float(u0 & 0xffff0000u);
        float l1 = f1 - __uint_as_float(u1 & 0xffff0000u);
        L.u[d] = (__float_as_uint(l1) & 0xffff0000u) | (__float_as_uint(l0) >> 16);
    }
    *hv = H.s; *lv = L.s;
}

// coherent (IF-direct) f32 store, relaxed
__device__ __forceinline__ void st_coh(float* p, float v) {
    __hip_atomic_store((unsigned*)p, __float_as_uint(v),
                       __ATOMIC_RELAXED, __HIP_MEMORY_SCOPE_AGENT);
}

// Grid barrier: monotonic hierarchical counters, all relaxed, no cache ops.
// 16 blocks per lvl-1 group. Spin: cnt2 >= ngrp*(tau+1).
__device__ __forceinline__ void gbar(unsigned* cnt1, unsigned* cnt2,
                                     unsigned tau, unsigned ngrp) {
    asm volatile("s_waitcnt vmcnt(0)" ::: "memory");   // drain coherent stores
    __syncthreads();
    if (threadIdx.x == 0) {
        unsigned old = __hip_atomic_fetch_add(&cnt1[blockIdx.x >> 4], 1u,
                                              __ATOMIC_RELAXED, __HIP_MEMORY_SCOPE_AGENT);
        if ((old & 15u) == 15u)
            __hip_atomic_fetch_add(cnt2, 1u, __ATOMIC_RELAXED, __HIP_MEMORY_SCOPE_AGENT);
        unsigned target = ngrp * (tau + 1u);
        while (__hip_atomic_load(cnt2, __ATOMIC_RELAXED, __HIP_MEMORY_SCOPE_AGENT) < target)
            __builtin_amdgcn_s_sleep(4);
    }
    __syncthreads();
    asm volatile("" ::: "memory");                     // no load hoisting above wake
}

// ---------------- split f32 -> (hi,lo) bf16 ----------------
__global__ __launch_bounds__(256) void split_f32(const float* __restrict__ src,
                                                 unsigned short* __restrict__ hi,
                                                 unsigned short* __restrict__ lo, int n) {
    int i = blockIdx.x * blockDim.x + threadIdx.x;
    int stride = gridDim.x * blockDim.x;
    for (; i < n; i += stride) {
        float v = src[i];
        unsigned short h = f2bf(v);
        hi[i] = h;
        lo[i] = f2bf(v - bf2f(h));
    }
}

// ---------------- split-bf16 MFMA GEMM (NT) ----------------
__global__ __launch_bounds__(256) void gemm_split(
    const float* __restrict__ A, const int* __restrict__ tokens,
    const unsigned short* __restrict__ Bhi, const unsigned short* __restrict__ Blo,
    const float* __restrict__ bias, float* __restrict__ C,
    int M, int N, int K, int tr96)
{
    __shared__ unsigned short Ah[64][40], Al[64][40];
    __shared__ unsigned short Bh[128][40], Bl[128][40];

    int t = threadIdx.x;
    int m0 = blockIdx.x * 64, n0 = blockIdx.y * 128;
    int wave = t >> 6, lane = t & 63;
    int wm = wave >> 1, wn = wave & 1;
    int kg = lane >> 4, r16 = lane & 15;

    f32x4 acc[2][4];
#pragma unroll
    for (int i = 0; i < 2; i++)
#pragma unroll
        for (int j = 0; j < 4; j++)
#pragma unroll
            for (int q = 0; q < 4; q++) acc[i][j][q] = 0.f;

    int ar = t >> 2, ac8 = (t & 3) * 8;
    long arow = -1;
    if (m0 + ar < M) arow = tokens ? (long)tokens[m0 + ar] : (long)(m0 + ar);

    for (int kt = 0; kt < K; kt += 32) {
        {
            short8 hv, lv;
            if (arow >= 0) {
                const float* ap = A + arow * (long)K + kt + ac8;
                f32x4 u0 = *(const f32x4*)ap;
                f32x4 u1 = *(const f32x4*)(ap + 4);
#pragma unroll
                for (int i = 0; i < 8; i++) {
                    float x = (i < 4) ? u0[i] : u1[i - 4];
                    unsigned short hb = f2bf(x);
                    hv[i] = (short)hb;
                    lv[i] = (short)f2bf(x - bf2f(hb));
                }
            } else {
#pragma unroll
                for (int i = 0; i < 8; i++) { hv[i] = 0; lv[i] = 0; }
            }
            *(short8*)&Ah[ar][ac8] = hv;
            *(short8*)&Al[ar][ac8] = lv;
        }
#pragma unroll
        for (int i = 0; i < 2; i++) {
            int idx = t + i * 256;
            int br = idx >> 2, bc8 = (idx & 3) * 8;
            long go = (long)(n0 + br) * K + kt + bc8;
            *(short8*)&Bh[br][bc8] = *(const short8*)(Bhi + go);
            *(short8*)&Bl[br][bc8] = *(const short8*)(Blo + go);
        }
        __syncthreads();

        short8 afh[2], afl[2], bfh[4], bfl[4];
#pragma unroll
        for (int m16 = 0; m16 < 2; m16++) {
            afh[m16] = *(short8*)&Ah[wm * 32 + m16 * 16 + r16][kg * 8];
            afl[m16] = *(short8*)&Al[wm * 32 + m16 * 16 + r16][kg * 8];
        }
#pragma unroll
        for (int n16 = 0; n16 < 4; n16++) {
            bfh[n16] = *(short8*)&Bh[wn * 64 + n16 * 16 + r16][kg * 8];
            bfl[n16] = *(short8*)&Bl[wn * 64 + n16 * 16 + r16][kg * 8];
        }
#pragma unroll
        for (int m16 = 0; m16 < 2; m16++)
#pragma unroll
            for (int n16 = 0; n16 < 4; n16++) {
                acc[m16][n16] = mfma16(afh[m16], bfh[n16], acc[m16][n16]);
                acc[m16][n16] = mfma16(afh[m16], bfl[n16], acc[m16][n16]);
                acc[m16][n16] = mfma16(afl[m16], bfh[n16], acc[m16][n16]);
            }
        __syncthreads();
    }

#pragma unroll
    for (int m16 = 0; m16 < 2; m16++)
#pragma unroll
        for (int n16 = 0; n16 < 4; n16++)
#pragma unroll
            for (int q = 0; q < 4; q++) {
                int row = m0 + wm * 32 + m16 * 16 + kg * 4 + q;
                int col = n0 + wn * 64 + n16 * 16 + r16;
                if (row < M) {
                    long crow = tr96 ? (long)((row % 96) * 96 + row / 96) : (long)row;
                    C[crow * N + col] = acc[m16][n16][q] + bias[col];
                }
            }
}

// ---------------- persistent word bi-GRU v5 (fresh-address coherence) -------
// 256 blocks x 384 thr (6 waves). block: msplit = blk>>7 (96 rows), 8-j slice.
// Whh hi+lo LDS-resident [arr][kg][brow 0-23][8] (96KB), filled once.
// h state IS bi: step-tau h[b=dir*96+s][k] = bi[(s*96+pos(dir,tau))*2048 + dir*1024 + k].
__global__ __launch_bounds__(384) void word_rnn(
    const unsigned short* __restrict__ Whi, const unsigned short* __restrict__ Wlo,
    const float* __restrict__ xWt,   // [96 pos][96 s][3072]
    const float* __restrict__ bhh, float* __restrict__ bi,
    unsigned* cnt1, unsigned* cnt2)
{
    __shared__ unsigned short Wh[2][128][24][8];    // 96KB

    int t = threadIdx.x;
    int blk = blockIdx.x;
    int msplit = blk >> 7;
    int j0 = (blk & 127) * 8;
    int w = t >> 6, lane = t & 63, kg4 = lane >> 4, r16 = lane & 15;

    // one-time Whh slice fill (stays L2/LDS resident; nothing invalidates it)
    for (int i = t; i < 4096; i += 384) {
        int kg = i >> 5, br = i & 31;
        if (br < 24) {
            long src = (long)((br >> 3) * 1024 + j0 + (br & 7)) * 1024 + kg * 8;
            *(short8*)&Wh[0][kg][br][0] = *(const short8*)(Whi + src);
            *(short8*)&Wh[1][kg][br][0] = *(const short8*)(Wlo + src);
        }
    }
    __syncthreads();

    int jj = r16 & 7;
    int j = j0 + jj;
    float b_r = bhh[j], b_z = bhh[1024 + j], b_n = bhh[2048 + j];
    int s_frag = w * 16 + r16;      // fragment row = sentence index

    f32x4 A0a, A0b, A1a, A1b, A2a, A2b, A3a, A3b;

#define LDW(Xa, Xb, ki)                                                   \
    do {                                                                  \
        const float* ap = abase + (ki) * 32;                              \
        Xa = *(const f32x4*)ap;                                           \
        Xb = *(const f32x4*)(ap + 4);                                     \
    } while (0)

#define DOW(Xa, Xb, ki, P)                                                \
    do {                                                                  \
        short8 ah, al;                                                    \
        split_win(Xa, Xb, &ah, &al);                                      \
        int kgB = (ki) * 4 + kg4;                                         \
        short8 b0h = *(short8*)&Wh[0][kgB][r16][0];                       \
        short8 b0l = *(short8*)&Wh[1][kgB][r16][0];                       \
        short8 b1h = *(short8*)&Wh[0][kgB][16 + jj][0];                   \
        short8 b1l = *(short8*)&Wh[1][kgB][16 + jj][0];                   \
        acc0##P = mfma16(ah, b0h, acc0##P);                               \
        acc0##P = mfma16(ah, b0l, acc0##P);                               \
        acc0##P = mfma16(al, b0h, acc0##P);                               \
        acc1##P = mfma16(ah, b1h, acc1##P);                               \
        acc1##P = mfma16(ah, b1l, acc1##P);                               \
        acc1##P = mfma16(al, b1h, acc1##P);                               \
    } while (0)

    for (int tau = 0; tau < 96; tau++) {
        int pos  = msplit ? (95 - tau) : tau;
        int posp = msplit ? (96 - tau) : (tau - 1);   // pos at step tau-1

        const float* abase = bi + ((long)s_frag * 96 + posp) * 2048 + msplit * 1024 + kg4 * 8;

        f32x4 acc0A, acc0B, acc1A, acc1B;
#pragma unroll
        for (int q = 0; q < 4; q++) { acc0A[q] = 0.f; acc0B[q] = 0.f; acc1A[q] = 0.f; acc1B[q] = 0.f; }

        // epilogue operands (xW cached; hprev cached — same rows as fragments)
        float xwv[4][3];
        float hpv[4];
#pragma unroll
        for (int q = 0; q < 4; q++) {
            if (r16 < 8) {
                int hloc = w * 16 + kg4 * 4 + q;
                const float* xp = xWt + ((long)pos * 96 + hloc) * 3072 + j;
                xwv[q][0] = xp[0];
                xwv[q][1] = xp[1024];
                xwv[q][2] = xp[2048];
                hpv[q] = (tau > 0) ? bi[((long)hloc * 96 + posp) * 2048 + msplit * 1024 + j] : 0.f;
            } else {
                xwv[q][0] = xwv[q][1] = xwv[q][2] = 0.f;
                hpv[q] = 0.f;
            }
        }

        if (tau > 0) {
            LDW(A0a, A0b, 0); LDW(A1a, A1b, 1); LDW(A2a, A2b, 2); LDW(A3a, A3b, 3);
#pragma unroll
            for (int kb = 0; kb < 32; kb += 4) {
                DOW(A0a, A0b, kb + 0, A); if (kb + 4 < 32) LDW(A0a, A0b, kb + 4);
                DOW(A1a, A1b, kb + 1, B); if (kb + 5 < 32) LDW(A1a, A1b, kb + 5);
                DOW(A2a, A2b, kb + 2, A); if (kb + 6 < 32) LDW(A2a, A2b, kb + 6);
                DOW(A3a, A3b, kb + 3, B); if (kb + 7 < 32) LDW(A3a, A3b, kb + 7);
            }
        }

        // epilogue: acc0 = {g0 (r16<8), g1 (r16>=8)}, acc1 = g2
#pragma unroll
        for (int q = 0; q < 4; q++) {
            float g0 = acc0A[q] + acc0B[q];
            float g1 = __shfl_xor(g0, 8);
            float g2 = acc1A[q] + acc1B[q];
            if (r16 < 8) {
                int hloc = w * 16 + kg4 * 4 + q;
                float rr = sigmoidf_(xwv[q][0] + g0 + b_r);
                float zz = sigmoidf_(xwv[q][1] + g1 + b_z);
                float nn = tanhf(xwv[q][2] + rr * (g2 + b_n));
                float hnew = (1.f - zz) * nn + zz * hpv[q];
                st_coh(bi + ((long)hloc * 96 + pos) * 2048 + msplit * 1024 + j, hnew);
            }
        }

        if (tau != 95) gbar(cnt1, cnt2, tau, 16);
    }
#undef LDW
#undef DOW
}

// ---------------- word attention ----------------
__global__ __launch_bounds__(256) void wscore(
    const float* __restrict__ bi, const float* __restrict__ wctx,
    const float* __restrict__ wctx_b, float* __restrict__ wsc)
{
    int tok = blockIdx.x * 4 + (threadIdx.x >> 6);
    int lane = threadIdx.x & 63;
    const float* row = bi + (long)tok * 2048 + lane * 32;
    const float* cp = wctx + lane * 32;
    float p = 0.f;
#pragma unroll
    for (int i = 0; i < 32; i += 4) {
        f32x4 v = *(const f32x4*)(row + i);
        f32x4 c = *(const f32x4*)(cp + i);
        p += v[0] * c[0] + v[1] * c[1] + v[2] * c[2] + v[3] * c[3];
    }
    p += __shfl_xor(p, 32); p += __shfl_xor(p, 16); p += __shfl_xor(p, 8);
    p += __shfl_xor(p, 4);  p += __shfl_xor(p, 2);  p += __shfl_xor(p, 1);
    if (lane == 0) wsc[tok] = expf(p + wctx_b[0]);
}

__global__ __launch_bounds__(256) void wsum(
    const float* __restrict__ bi, const float* __restrict__ wsc,
    float* __restrict__ sent_vecs)
{
    int s = blockIdx.x;
    int c = blockIdx.y * 256 + threadIdx.x;
    float acc = 0.f;
    for (int tk = 0; tk < 96; tk++)
        acc += wsc[s * 96 + tk] * bi[((long)s * 96 + tk) * 2048 + c];
    sent_vecs[(long)s * 2048 + c] = acc;
}

// ---------------- persistent sentence bi-GRU (fresh-address coherence) ------
// 128 blocks x 256 thr; sWhh f32 slice (24 rows x 1024) LDS-resident.
// h state IS sbi: step-tau h[bq][j] = sbi[pos(bq,tau)*2048 + bq*1024 + j].
__global__ __launch_bounds__(256) void sent_rnn(
    const float* __restrict__ sWhh, const float* __restrict__ xWs,
    const float* __restrict__ sbhh, float* __restrict__ sbi,
    unsigned* cnt1, unsigned* cnt2)
{
    __shared__ float Wl[24 * 1028];
    __shared__ float hsh[2048];
    __shared__ float part[4][48];

    int t = threadIdx.x;
    int j0 = blockIdx.x * 8;
    int w = t >> 6, lane = t & 63;

    for (int i = t; i < 24 * 1024; i += 256) {
        int row = i >> 10, k = i & 1023;
        Wl[row * 1028 + k] = sWhh[(long)((row >> 3) * 1024 + j0 + (row & 7)) * 1024 + k];
    }

    for (int tau = 0; tau < 96; tau++) {
        int posp0 = tau - 1, posp1 = 96 - tau;
        __syncthreads();
        for (int i = t; i < 2048; i += 256) {
            int bq = i >> 10, k = i & 1023;
            int pp = bq ? posp1 : posp0;
            hsh[i] = (tau > 0) ? sbi[(long)pp * 2048 + bq * 1024 + k] : 0.f;
        }
        __syncthreads();

        if (lane < 48) {
            int row = lane >> 1, bq = lane & 1;
            const float* wp = &Wl[row * 1028 + w * 256];
            const float* hp = &hsh[bq * 1024 + w * 256];
            float accd = 0.f;
            for (int k = 0; k < 256; k += 4) {
                f32x4 wv = *(const f32x4*)(wp + k);
                f32x4 hv = *(const f32x4*)(hp + k);
                accd += wv[0] * hv[0] + wv[1] * hv[1] + wv[2] * hv[2] + wv[3] * hv[3];
            }
            part[w][lane] = accd;
        }
        __syncthreads();

        if (t < 16) {
            int jl2 = t >> 1, bq = t & 1;
            int jv = j0 + jl2;
            int pos = bq ? (95 - tau) : tau;
            int pp  = bq ? posp1 : posp0;
            const float* xp = xWs + (long)pos * 3072;
            int d0 = (0 * 8 + jl2) * 2 + bq;
            int d1 = (1 * 8 + jl2) * 2 + bq;
            int d2 = (2 * 8 + jl2) * 2 + bq;
            float D0 = part[0][d0] + part[1][d0] + part[2][d0] + part[3][d0];
            float D1 = part[0][d1] + part[1][d1] + part[2][d1] + part[3][d1];
            float D2 = part[0][d2] + part[1][d2] + part[2][d2] + part[3][d2];
            float rr = sigmoidf_(xp[jv] + D0 + sbhh[jv]);
            float zz = sigmoidf_(xp[1024 + jv] + D1 + sbhh[1024 + jv]);
            float nn = tanhf(xp[2048 + jv] + rr * (D2 + sbhh[2048 + jv]));
            float hprev = (tau > 0) ? sbi[(long)pp * 2048 + bq * 1024 + jv] : 0.f;
            float hnew = (1.f - zz) * nn + zz * hprev;
            st_coh(sbi + (long)pos * 2048 + bq * 1024 + jv, hnew);
        }

        if (tau != 95) gbar(cnt1, cnt2, tau, 8);
    }
}

// ---------------- sentence attention ----------------
__global__ __launch_bounds__(256) void sent_scores(
    const float* __restrict__ sbi, const float* __restrict__ sctx,
    const float* __restrict__ sctx_b, float* __restrict__ scores)
{
    __shared__ float red[4];
    int s = blockIdx.x, t = threadIdx.x, c = t * 8;
    const float* row = sbi + (long)s * 2048 + c;
    float p = 0.f;
#pragma unroll
    for (int i = 0; i < 8; i++) p += row[i] * sctx[c + i];
    p += __shfl_xor(p, 32); p += __shfl_xor(p, 16); p += __shfl_xor(p, 8);
    p += __shfl_xor(p, 4);  p += __shfl_xor(p, 2);  p += __shfl_xor(p, 1);
    int lane = t & 63, w = t >> 6;
    if (lane == 0) red[w] = p;
    __syncthreads();
    if (t == 0) scores[s] = expf(red[0] + red[1] + red[2] + red[3] + sctx_b[0]);
}

__global__ __launch_bounds__(256) void doc_out(
    const float* __restrict__ sbi, const float* __restrict__ scores,
    float* __restrict__ out)
{
    int t = threadIdx.x, c = t * 8;
    float acc[8];
#pragma unroll
    for (int i = 0; i < 8; i++) acc[i] = 0.f;
    for (int s = 0; s < 96; s++) {
        float sc = scores[s];
        const float* row = sbi + (long)s * 2048 + c;
#pragma unroll
        for (int i = 0; i < 8; i++) acc[i] += sc * row[i];
    }
#pragma unroll
    for (int i = 0; i < 8; i++) out[c + i] = acc[i];
}

// ---------------- host ----------------
extern "C" void kernel_launch(void* const* d_in, const int* in_sizes, int n_in,
                              void* d_out, int out_size, void* d_ws, size_t ws_size,
                              hipStream_t stream)
{
    const int*   tokens    = (const int*)  d_in[0];
    const float* embedding = (const float*)d_in[1];
    const float* wWih = (const float*)d_in[2];
    const float* wWhh = (const float*)d_in[3];
    const float* wbih = (const float*)d_in[4];
    const float* wbhh = (const float*)d_in[5];
    const float* sWih = (const float*)d_in[6];
    const float* sWhh = (const float*)d_in[7];
    const float* sbih = (const float*)d_in[8];
    const float* sbhh = (const float*)d_in[9];
    const float* wctxw = (const float*)d_in[10];
    const float* wctxb = (const float*)d_in[11];
    const float* sctxw = (const float*)d_in[12];
    const float* sctxb = (const float*)d_in[13];
    float* out = (float*)d_out;

    char* p = (char*)d_ws;
    auto alloc = [&](size_t bytes) -> char* {
        char* r = p;
        p += (bytes + 255) & ~(size_t)255;
        return r;
    };
    unsigned short* WihHi  = (unsigned short*)alloc(3072l * 1024 * 2);
    unsigned short* WihLo  = (unsigned short*)alloc(3072l * 1024 * 2);
    unsigned short* WhhHi  = (unsigned short*)alloc(3072l * 1024 * 2);
    unsigned short* WhhLo  = (unsigned short*)alloc(3072l * 1024 * 2);
    unsigned short* sWihHi = (unsigned short*)alloc(3072l * 2048 * 2);
    unsigned short* sWihLo = (unsigned short*)alloc(3072l * 2048 * 2);
    float* xWt       = (float*)alloc(9216l * 3072 * 4);   // [pos][s][3072]
    float* bi        = (float*)alloc(9216l * 2048 * 4);   // also word h state
    float* sent_vecs = (float*)alloc(96l * 2048 * 4);
    float* xWs       = (float*)alloc(96l * 3072 * 4);
    float* sbi       = (float*)alloc(96l * 2048 * 4);     // also sent h state
    float* scores    = (float*)alloc(512);
    float* wsc       = (float*)alloc(9216l * 4);
    unsigned* barbuf = (unsigned*)alloc(256);
    (void)ws_size; (void)in_sizes; (void)n_in; (void)out_size;

    hipMemsetAsync(barbuf, 0, 256, stream);

    split_f32<<<1024, 256, 0, stream>>>(wWih, WihHi, WihLo, 3072 * 1024);
    split_f32<<<1024, 256, 0, stream>>>(wWhh, WhhHi, WhhLo, 3072 * 1024);
    split_f32<<<1024, 256, 0, stream>>>(sWih, sWihHi, sWihLo, 3072 * 2048);

    // word input projection, stored transposed: xWt[pos][s][3072]
    gemm_split<<<dim3(144, 24), 256, 0, stream>>>(
        embedding, tokens, WihHi, WihLo, wbih, xWt, 9216, 3072, 1024, 1);

    // persistent word bi-GRU (96 steps internally, zero cache maintenance)
    word_rnn<<<256, 384, 0, stream>>>(
        WhhHi, WhhLo, xWt, wbhh, bi, barbuf + 0, barbuf + 16);

    // word attention
    wscore<<<2304, 256, 0, stream>>>(bi, wctxw, wctxb, wsc);
    wsum<<<dim3(96, 8), 256, 0, stream>>>(bi, wsc, sent_vecs);

    // sentence input projection: xWs[pos][3072]
    gemm_split<<<dim3(2, 24), 256, 0, stream>>>(
        sent_vecs, nullptr, sWihHi, sWihLo, sbih, xWs, 96, 3072, 2048, 0);

    // persistent sentence bi-GRU
    sent_rnn<<<128, 256, 0, stream>>>(
        sWhh, xWs, sbhh, sbi, barbuf + 32, barbuf + 48);

    sent_scores<<<96, 256, 0, stream>>>(sbi, sctxw, sctxb, scores);
    doc_out<<<1, 256, 0, stream>>>(sbi, scores, out);
}